// Round 1
// 724.404 us; speedup vs baseline: 1.0858x; 1.0858x over previous
//
#include <hip/hip_runtime.h>
#include <stdint.h>

// VQ-VAE codebook quantize: z (8,256,16,32,32) f32, codebook (1024,256) f32.
// Outputs (concat in d_out, f32): quantized, st (== quantized fwd), indices.
// R5: sweep rebuilt as 256x256-tile 8-wave pipelined GEMM (counted vmcnt(8),
// raw barriers, double-buffered 128KiB LDS, setprio) + packed-uint argmin
// epilogue (zn dropped — it cancels in argmin/window). Numerics of the MFMA
// chain are bit-identical to R4; window widened 2.0e-3 -> 2.2e-3 to absorb
// the 10-bit packed-score quantization (<= ~2e-5).

constexpr int Dd  = 256;
constexpr int SPB = 16384;          // 16*32*32
constexpr int Nn  = 131072;         // 8*SPB tokens
constexpr int Kk  = 1024;
constexpr int CCAP = 16;            // candidate cap per token (avg ~1.2, P(>16)~0)
#define WWIN 2.2e-3f                // collect window; >= 2x approx err + quant

typedef short short8 __attribute__((ext_vector_type(8)));
typedef float v4f    __attribute__((ext_vector_type(4)));

__device__ __forceinline__ unsigned bf16pk(float a, float b){  // RNE pack 2xbf16
  unsigned ua = __float_as_uint(a), ub = __float_as_uint(b);
  ua = (ua + 0x7fffu + ((ua >> 16) & 1u)) >> 16;
  ub = (ub + 0x7fffu + ((ub >> 16) & 1u)) & 0xffff0000u;
  return ua | ub;
}
__device__ __forceinline__ short8 frg(uint4 u){
  union { uint4 a; short8 b; } x; x.a = u; return x.b;
}
__device__ __forceinline__ v4f mfma16(short8 a, short8 b, v4f c){
  return __builtin_amdgcn_mfma_f32_16x16x32_bf16(a, b, c, 0, 0, 0);
}
__device__ __forceinline__ void dma16(const void* g, void* l){
  __builtin_amdgcn_global_load_lds((const __attribute__((address_space(1))) void*)g,
                                   (__attribute__((address_space(3))) void*)l, 16, 0, 0);
}

// ---------- prepass: ||e_k||^2 ----------
__global__ __launch_bounds__(64) void cnorm_k(const float* __restrict__ cb,
                                              float* __restrict__ cn){
  const int k = blockIdx.x, l = threadIdx.x;
  const float* row = cb + (size_t)k * Dd;
  float s = 0.f;
  #pragma unroll
  for (int c = 0; c < Dd; c += 64){ float v = row[c + l]; s += v * v; }
  #pragma unroll
  for (int off = 32; off > 0; off >>= 1) s += __shfl_down(s, off, 64);
  if (l == 0) cn[k] = s;
}

// ---------- prepass: codebook -> bf16 hi fragment plane ----------
// Bg: [cc 0..3][dc 0..7][kq 0..3][n 0..255] x 16B
__global__ __launch_bounds__(256) void cconv_k(const float* __restrict__ cb,
                                               uint4* __restrict__ Bg){
  const int cc = blockIdx.x, n = threadIdx.x;
  const float* row = cb + (size_t)(cc * 256 + n) * Dd;
  for (int dc = 0; dc < 8; dc++){
    float v[32];
    const float4* rp = (const float4*)(row + dc * 32);
    #pragma unroll
    for (int q = 0; q < 8; q++){
      float4 f = rp[q]; v[4*q]=f.x; v[4*q+1]=f.y; v[4*q+2]=f.z; v[4*q+3]=f.w;
    }
    unsigned hv[16];
    #pragma unroll
    for (int p = 0; p < 16; p++) hv[p] = bf16pk(v[2*p], v[2*p+1]);
    size_t base = ((size_t)cc * 8 + dc) * 1024;
    #pragma unroll
    for (int kq = 0; kq < 4; kq++)
      Bg[base + (size_t)kq*256 + n] = make_uint4(hv[4*kq],hv[4*kq+1],hv[4*kq+2],hv[4*kq+3]);
  }
}

// ---------- prepass: z -> bf16 hi fragment plane ----------
// Ag: [blk 0..1023][dc 0..7][kq 0..3][m 0..127] x 16B
__global__ __launch_bounds__(256) void zconv_k(const float* __restrict__ z,
                                               uint4* __restrict__ Ag){
  const int tid = threadIdx.x, blk = blockIdx.x;
  const int b = blk >> 7, sb = (blk & 127) * 128;
  const int m = tid & 127, kqh = tid >> 7;
  const float* zb = z + (size_t)b * Dd * SPB + sb + m;
  for (int dc = 0; dc < 8; dc++){
    float v[16];
    #pragma unroll
    for (int s = 0; s < 16; s++) v[s] = zb[(size_t)(dc*32 + kqh*16 + s) * SPB];
    unsigned hv[8];
    #pragma unroll
    for (int p = 0; p < 8; p++) hv[p] = bf16pk(v[2*p], v[2*p+1]);
    size_t base = ((size_t)blk * 8 + dc) * 512;
    Ag[base + (size_t)(kqh*2+0)*128 + m] = make_uint4(hv[0],hv[1],hv[2],hv[3]);
    Ag[base + (size_t)(kqh*2+1)*128 + m] = make_uint4(hv[4],hv[5],hv[6],hv[7]);
  }
}

// ---------- phase 1: pipelined MFMA sweep + packed argmin + window collect ----
// 512 threads = 8 waves (2 token-halves x 4 code-quarters). Tile: 256 tokens x
// 256 codes (cc loop over 4 chunks), BK=64 (2 dc per K-step), 2x double-buffered
// LDS (128 KiB), counted vmcnt(8), raw s_barrier (no vmcnt drain in main loop).
__global__ __launch_bounds__(512) void vq_sweep_k(const uint4* __restrict__ Ag,
                                                  const uint4* __restrict__ Bg,
                                                  const float* __restrict__ cnG,
                                                  int* __restrict__ cntW,
                                                  unsigned short* __restrict__ candW,
                                                  int* __restrict__ abestW){
  __shared__ uint4 AswF[2][2048];            // 64 KiB  [buf][dcL][kq][m256]
  __shared__ uint4 BswF[2][2048];            // 64 KiB  [buf][dcL][kq][n256]
  __shared__ unsigned bestP[256];            // packed (score|code) running min
  __shared__ int cnt[256];
  __shared__ uint4 candU[256][2];            // 256 x 16 ushort candidates
  unsigned short* cand = (unsigned short*)candU;

  const int tid = threadIdx.x, bId = blockIdx.x;
  const int w = tid >> 6, ln = tid & 63;
  const int li = ln & 15, lq = ln >> 4;
  const int wm = w >> 2, wn = w & 3;

  if (tid < 256){ bestP[tid] = 0xFFFFFFFFu; cnt[tid] = 0; }

  float cnr[4][4];
  #pragma unroll
  for (int cc = 0; cc < 4; cc++)
    #pragma unroll
    for (int ni = 0; ni < 4; ni++)
      cnr[cc][ni] = cnG[cc*256 + wn*64 + ni*16 + li];

  // per-thread staging source offsets (constant across K-steps)
  int aOff[4], bOff[4];
  #pragma unroll
  for (int c = 0; c < 4; c++){
    const int f = c*512 + w*64 + ln;          // [dcL][kq][m] flat
    const int dcL = f >> 10, kq = (f >> 8) & 3, mn = f & 255;
    aOff[c] = ((2*bId + (mn >> 7))*8 + dcL)*512 + kq*128 + (mn & 127);
    bOff[c] = dcL*1024 + kq*256 + mn;
  }

  // prologue: stage ks=0 -> buf0
  #pragma unroll
  for (int c = 0; c < 4; c++) dma16(Ag + aOff[c], &AswF[0][c*512 + w*64]);
  #pragma unroll
  for (int c = 0; c < 4; c++) dma16(Bg + bOff[c], &BswF[0][c*512 + w*64]);

  v4f acc[8][4];
  #pragma unroll
  for (int cc = 0; cc < 4; cc++){
    const v4f vz = {0.f, 0.f, 0.f, 0.f};
    #pragma unroll
    for (int mi = 0; mi < 8; mi++)
      #pragma unroll
      for (int ni = 0; ni < 4; ni++) acc[mi][ni] = vz;

    #pragma unroll
    for (int ksq = 0; ksq < 4; ksq++){
      const int ks = cc*4 + ksq;
      if (ks < 15){
        const int ksn = ks + 1, bufn = ksn & 1, kqn = ksn & 3;
        #pragma unroll
        for (int c = 0; c < 4; c++)
          dma16(Ag + aOff[c] + kqn*1024, &AswF[bufn][c*512 + w*64]);
        #pragma unroll
        for (int c = 0; c < 4; c++)
          dma16(Bg + bOff[c] + ksn*2048, &BswF[bufn][c*512 + w*64]);
        asm volatile("s_waitcnt vmcnt(8)" ::: "memory");   // own ks-loads done
      } else {
        asm volatile("s_waitcnt vmcnt(0)" ::: "memory");
      }
      __builtin_amdgcn_s_barrier();                        // all waves' loads done
      asm volatile("" ::: "memory");

      const int buf = ks & 1;
      #pragma unroll
      for (int dcL = 0; dcL < 2; dcL++){
        const uint4* Ab = &AswF[buf][dcL*1024 + lq*256 + wm*128 + li];
        const uint4* Bb = &BswF[buf][dcL*1024 + lq*256 + wn*64  + li];
        uint4 b0 = Bb[0], b1 = Bb[16], b2 = Bb[32], b3 = Bb[48];
        __builtin_amdgcn_s_setprio(1);
        #pragma unroll
        for (int mi = 0; mi < 8; mi++){
          uint4 av = Ab[mi*16];
          acc[mi][0] = mfma16(frg(av), frg(b0), acc[mi][0]);
          acc[mi][1] = mfma16(frg(av), frg(b1), acc[mi][1]);
          acc[mi][2] = mfma16(frg(av), frg(b2), acc[mi][2]);
          acc[mi][3] = mfma16(frg(av), frg(b3), acc[mi][3]);
        }
        __builtin_amdgcn_s_setprio(0);
      }
      asm volatile("s_waitcnt lgkmcnt(0)" ::: "memory");   // reads of buf done
      __builtin_amdgcn_s_barrier();                        // safe to overwrite buf
      asm volatile("" ::: "memory");
    }

    // ---- per-chunk epilogue: packed (score|code) argmin + window collect ----
    const int codeB = cc*256 + wn*64 + li;
    #pragma unroll
    for (int mi = 0; mi < 8; mi++){
      #pragma unroll
      for (int r = 0; r < 4; r++){
        unsigned pm = 0xFFFFFFFFu;
        #pragma unroll
        for (int ni = 0; ni < 4; ni++){
          float s = fmaf(acc[mi][ni][r], -2.0f, cnr[cc][ni]);   // zn cancels
          unsigned u = __float_as_uint(s);
          u ^= (unsigned)((int)u >> 31) | 0x80000000u;          // sortable uint
          unsigned p = (u & 0xFFFFFC00u) | (unsigned)(codeB + ni*16);
          acc[mi][ni][r] = __uint_as_float(p);                  // stash for collect
          pm = (pm < p) ? pm : p;
        }
        #pragma unroll
        for (int off = 1; off < 16; off <<= 1){
          unsigned o = (unsigned)__shfl_xor((int)pm, off, 16);
          pm = (pm < o) ? pm : o;
        }
        if (li == 0) atomicMin(&bestP[wm*128 + mi*16 + lq*4 + r], pm);
      }
    }
    asm volatile("s_waitcnt lgkmcnt(0)" ::: "memory");
    __builtin_amdgcn_s_barrier();
    asm volatile("" ::: "memory");
    #pragma unroll
    for (int mi = 0; mi < 8; mi++){
      #pragma unroll
      for (int r = 0; r < 4; r++){
        const int row = wm*128 + mi*16 + lq*4 + r;
        unsigned bp = bestP[row] & 0xFFFFFC00u;
        unsigned fb = (bp & 0x80000000u) ? (bp ^ 0x80000000u) : ~bp;  // unpack
        float thr = __uint_as_float(fb) + WWIN;
        unsigned tu = __float_as_uint(thr);
        tu ^= (unsigned)((int)tu >> 31) | 0x80000000u;
        tu |= 1023u;                                          // inclusive of code
        #pragma unroll
        for (int ni = 0; ni < 4; ni++){
          unsigned p = __float_as_uint(acc[mi][ni][r]);
          if (p <= tu){
            int pos = atomicAdd(&cnt[row], 1);
            if (pos < CCAP) cand[row*CCAP + pos] = (unsigned short)(p & 1023u);
          }
        }
      }
    }
    // no trailing barrier: next chunk's K-step barriers order E2 vs next E1
  }

  asm volatile("s_waitcnt lgkmcnt(0)" ::: "memory");
  __builtin_amdgcn_s_barrier();
  asm volatile("" ::: "memory");
  if (tid < 256){
    const int tok = bId*256 + tid;
    cntW[tok] = cnt[tid];
    abestW[tok] = (int)(bestP[tid] & 1023u);
    uint4* dst = (uint4*)&candW[(size_t)tok * CCAP];
    dst[0] = candU[tid][0];
    dst[1] = candU[tid][1];
  }
}

// ---------- phase 2: exact fp32 rescore (R3-proven arithmetic), 1 thread/token ----------
__global__ __launch_bounds__(256) void vq_rescore_k(const float* __restrict__ z,
                                                    const float* __restrict__ cb,
                                                    const float* __restrict__ cnG,
                                                    const int* __restrict__ cntW,
                                                    const unsigned short* __restrict__ candW,
                                                    const int* __restrict__ abestW,
                                                    int* __restrict__ idsW,
                                                    float* __restrict__ out){
  const int tok = blockIdx.x * 256 + threadIdx.x;
  const int b = tok >> 14, s = tok & 16383;
  const float* zr = z + (size_t)b * Dd * SPB + s;

  int n = cntW[tok];
  const bool ovf = (n > CCAP);
  if (ovf) n = CCAP;
  unsigned short cds[CCAP];
  *(uint4*)&cds[0] = *(const uint4*)&candW[(size_t)tok * CCAP];
  *(uint4*)&cds[8] = *(const uint4*)&candW[(size_t)tok * CCAP + 8];

  float bv = 3.4e38f; int bi = 0x7fffffff;
  float znl = 0.f;
  const int ngroups = (n + 3) >> 2;
  const int total = ovf ? ngroups + 1 : ngroups;

  for (int g = 0; g < total; g++){
    int idxs[4];
    #pragma unroll
    for (int ss = 0; ss < 4; ss++){
      int slot = g*4 + ss; if (slot >= n) slot = n - 1;
      idxs[ss] = (g < ngroups) ? (int)cds[slot] : abestW[tok];
    }
    const float* cr0 = cb + (size_t)idxs[0] * Dd;
    const float* cr1 = cb + (size_t)idxs[1] * Dd;
    const float* cr2 = cb + (size_t)idxs[2] * Dd;
    const float* cr3 = cb + (size_t)idxs[3] * Dd;
    float a0=0.f, a1=0.f, a2=0.f, a3=0.f, za=0.f;
    for (int d = 0; d < Dd; d += 8){
      float zv[8];
      #pragma unroll
      for (int j = 0; j < 8; j++) zv[j] = zr[(size_t)(d + j) * SPB];
      float4 c0a = *(const float4*)(cr0 + d), c0b = *(const float4*)(cr0 + d + 4);
      float4 c1a = *(const float4*)(cr1 + d), c1b = *(const float4*)(cr1 + d + 4);
      float4 c2a = *(const float4*)(cr2 + d), c2b = *(const float4*)(cr2 + d + 4);
      float4 c3a = *(const float4*)(cr3 + d), c3b = *(const float4*)(cr3 + d + 4);
      float cv0[8] = {c0a.x,c0a.y,c0a.z,c0a.w,c0b.x,c0b.y,c0b.z,c0b.w};
      float cv1[8] = {c1a.x,c1a.y,c1a.z,c1a.w,c1b.x,c1b.y,c1b.z,c1b.w};
      float cv2[8] = {c2a.x,c2a.y,c2a.z,c2a.w,c2b.x,c2b.y,c2b.z,c2b.w};
      float cv3[8] = {c3a.x,c3a.y,c3a.z,c3a.w,c3b.x,c3b.y,c3b.z,c3b.w};
      #pragma unroll
      for (int j = 0; j < 8; j++){
        if (g == 0) za = fmaf(zv[j], zv[j], za);
        a0 = fmaf(zv[j], cv0[j], a0);
        a1 = fmaf(zv[j], cv1[j], a1);
        a2 = fmaf(zv[j], cv2[j], a2);
        a3 = fmaf(zv[j], cv3[j], a3);
      }
    }
    if (g == 0) znl = za;
    float av[4] = {a0, a1, a2, a3};
    const int lim = (g < ngroups) ? n : 1;
    #pragma unroll
    for (int ss = 0; ss < 4; ss++){
      if (g*4 + ss < lim || (g >= ngroups && ss == 0)){
        float t  = znl - 2.0f * av[ss];
        float d2 = t + cnG[idxs[ss]];
        if (d2 < bv || (d2 == bv && idxs[ss] < bi)){ bv = d2; bi = idxs[ss]; }
      }
    }
  }
  idsW[tok] = bi;
  out[(size_t)2 * Nn * Dd + tok] = (float)bi;
}

// ---------- phase 3: LDS-transpose gather ----------
__global__ __launch_bounds__(256) void vq_gather_k(const float* __restrict__ cb,
                                                   const int* __restrict__ idsW,
                                                   float* __restrict__ out){
  __shared__ float tile[64][129];
  __shared__ int lid[64];
  const int tid = threadIdx.x, blk = blockIdx.x;   // 2048 blocks
  const int b = blk >> 8, s0 = (blk & 255) * 64;
  if (tid < 64) lid[tid] = idsW[b * SPB + s0 + tid];
  __syncthreads();

  const int r2 = tid >> 7, c = tid & 127;          // load mapping
  const int s = tid & 63, cq = tid >> 6;           // store mapping
  float* qb  = out + (size_t)b * Dd * SPB + s0 + s;
  float* stb = qb + (size_t)Nn * Dd;

  for (int ch = 0; ch < 2; ch++){
    #pragma unroll 4
    for (int t0 = 0; t0 < 64; t0 += 2){
      const int row = t0 + r2;
      tile[row][c] = cb[(size_t)lid[row] * Dd + ch*128 + c];
    }
    __syncthreads();
    #pragma unroll 8
    for (int i = 0; i < 32; i++){
      const int cc2 = i*4 + cq;
      const float v = tile[s][cc2];
      const size_t off = (size_t)(ch*128 + cc2) * SPB;
      qb[off]  = v;
      stb[off] = v;
    }
    __syncthreads();
  }
}

// ================= R1 fp32 fallback (used if ws too small) =================
#define MICRO_STEP(WITH_ZN)                                                    \
    {                                                                          \
        float4 a0 = *(const float4*)&As[d][ty * 8];                            \
        float4 a1 = *(const float4*)&As[d][ty * 8 + 4];                        \
        float4 b0 = *(const float4*)&Bs[d][tx * 8];                            \
        float4 b1 = *(const float4*)&Bs[d][tx * 8 + 4];                        \
        float a[8] = {a0.x, a0.y, a0.z, a0.w, a1.x, a1.y, a1.z, a1.w};         \
        float bb[8] = {b0.x, b0.y, b0.z, b0.w, b1.x, b1.y, b1.z, b1.w};        \
        _Pragma("unroll")                                                      \
        for (int i = 0; i < 8; i++) {                                          \
            _Pragma("unroll")                                                  \
            for (int j = 0; j < 8; j++) acc[i][j] += a[i] * bb[j];             \
            if (WITH_ZN) zn[i] += a[i] * a[i];                                 \
        }                                                                      \
    }

__global__ __launch_bounds__(256) void vq_k(const float* __restrict__ z,
                                            const float* __restrict__ cb,
                                            const float* __restrict__ cn,
                                            float* __restrict__ out){
  __shared__ float As[16][128];
  __shared__ float Bs[16][132];
  __shared__ int   idsf[128];
  const int tid = threadIdx.x;
  const int tx = tid & 15, ty = tid >> 4;
  const int blk = blockIdx.x;
  const int b = blk >> 7, sb = (blk & 127) * 128;
  const float* zb = z + (size_t)b * Dd * SPB + sb;
  float bestv[8]; int besti[8]; float zn[8];
  #pragma unroll
  for (int i = 0; i < 8; i++){ bestv[i] = 3.4e38f; besti[i] = 0; zn[i] = 0.f; }
  const int am = tid & 127, ad = tid >> 7;
  const int bd = tid & 15,  bk = tid >> 4;
  for (int cc = 0; cc < 8; cc++){
    float acc[8][8];
    #pragma unroll
    for (int i = 0; i < 8; i++)
      #pragma unroll
      for (int j = 0; j < 8; j++) acc[i][j] = 0.f;
    for (int dc = 0; dc < 16; dc++){
      #pragma unroll
      for (int r = 0; r < 8; r++){
        const int d = ad + r * 2;
        As[d][am] = zb[(size_t)(dc*16 + d) * SPB + am];
      }
      #pragma unroll
      for (int r = 0; r < 8; r++){
        const int k = bk + r * 16;
        Bs[bd][k] = cb[(size_t)(cc*128 + k) * Dd + dc*16 + bd];
      }
      __syncthreads();
      if (cc == 0){
        #pragma unroll
        for (int d = 0; d < 16; d++) MICRO_STEP(1)
      } else {
        #pragma unroll
        for (int d = 0; d < 16; d++) MICRO_STEP(0)
      }
      __syncthreads();
    }
    const float* cnp = cn + cc*128 + tx*8;
    float4 c0 = *(const float4*)cnp;
    float4 c1 = *(const float4*)(cnp + 4);
    float cv[8] = {c0.x, c0.y, c0.z, c0.w, c1.x, c1.y, c1.z, c1.w};
    #pragma unroll
    for (int i = 0; i < 8; i++){
      #pragma unroll
      for (int j = 0; j < 8; j++){
        float t  = zn[i] - 2.0f * acc[i][j];
        float d2 = t + cv[j];
        int   ix = cc*128 + tx*8 + j;
        if (d2 < bestv[i]){ bestv[i] = d2; besti[i] = ix; }
      }
    }
  }
  #pragma unroll
  for (int i = 0; i < 8; i++){
    float v = bestv[i]; int ix = besti[i];
    #pragma unroll
    for (int off = 8; off > 0; off >>= 1){
      float ov = __shfl_down(v, off, 16);
      int   oi = __shfl_down(ix, off, 16);
      if (ov < v || (ov == v && oi < ix)){ v = ov; ix = oi; }
    }
    if (tx == 0) idsf[ty*8 + i] = ix;
  }
  __syncthreads();
  if (tid < 128) out[(size_t)2*Nn*Dd + (size_t)blk*128 + tid] = (float)idsf[tid];
  const int m = tid & 127, cg = tid >> 7;
  const int myidx = idsf[m];
  const float* crow = cb + (size_t)myidx * Dd + cg*128;
  float* q  = out + (size_t)b * Dd * SPB + (size_t)cg * 128 * SPB + sb + m;
  float* st = q + (size_t)Nn * Dd;
  #pragma unroll 8
  for (int r = 0; r < 128; r++){
    const float v = crow[r];
    q[(size_t)r * SPB]  = v;
    st[(size_t)r * SPB] = v;
  }
}

// ---------- launcher ----------
extern "C" void kernel_launch(void* const* d_in, const int* in_sizes, int n_in,
                              void* d_out, int out_size, void* d_ws, size_t ws_size,
                              hipStream_t stream){
  const float* z  = (const float*)d_in[0];
  const float* cb = (const float*)d_in[1];
  float* out = (float*)d_out;

  const size_t AG_B  = (size_t)1024 * 8 * 512 * 16;   // 64 MiB
  const size_t BG_B  = (size_t)4 * 8 * 1024 * 16;     // 512 KiB
  const size_t CN_B  = (size_t)Kk * 4;                // 4 KiB
  const size_t CNT_B = (size_t)Nn * 4;                // 512 KiB
  const size_t CAN_B = (size_t)Nn * CCAP * 2;         // 4 MiB
  const size_t ABW_B = (size_t)Nn * 4;                // 512 KiB
  const size_t IDS_B = (size_t)Nn * 4;                // 512 KiB
  const size_t NEED = AG_B + BG_B + CN_B + CNT_B + CAN_B + ABW_B + IDS_B;

  if (ws_size >= NEED){
    uint8_t* ws = (uint8_t*)d_ws;
    size_t o = 0;
    uint4* Ag   = (uint4*)(ws + o);          o += AG_B;
    uint4* Bg   = (uint4*)(ws + o);          o += BG_B;
    float* cnG  = (float*)(ws + o);          o += CN_B;
    int*   cntW = (int*)(ws + o);            o += CNT_B;
    unsigned short* candW = (unsigned short*)(ws + o); o += CAN_B;
    int*   abW  = (int*)(ws + o);            o += ABW_B;
    int*   idsW = (int*)(ws + o);            o += IDS_B;

    cnorm_k<<<Kk, 64, 0, stream>>>(cb, cnG);
    cconv_k<<<4, 256, 0, stream>>>(cb, Bg);
    zconv_k<<<Nn/128, 256, 0, stream>>>(z, Ag);
    vq_sweep_k<<<Nn/256, 512, 0, stream>>>(Ag, Bg, cnG, cntW, candW, abW);
    vq_rescore_k<<<Nn/256, 256, 0, stream>>>(z, cb, cnG, cntW, candW, abW, idsW, out);
    vq_gather_k<<<Nn/64, 256, 0, stream>>>(cb, idsW, out);
  } else {
    float* cn = (float*)d_ws;
    cnorm_k<<<Kk, 64, 0, stream>>>(cb, cn);
    vq_k<<<Nn/128, 256, 0, stream>>>(z, cb, cn, out);
  }
}

// Round 2
// 717.747 us; speedup vs baseline: 1.0959x; 1.0093x over previous
//
#include <hip/hip_runtime.h>
#include <stdint.h>

// VQ-VAE codebook quantize: z (8,256,16,32,32) f32, codebook (1024,256) f32.
// Outputs (concat in d_out, f32): quantized, st (== quantized fwd), indices.
// R6: sweep restructured — A (z) held in registers per wave (loaded once,
// straight from z with the verified bf16pk chain; zconv + Ag plane DELETED),
// B streamed via 2x32KiB LDS double-buffer (counted vmcnt, raw barriers).
// LDS 68KiB -> 2 blocks/CU (16 waves, independent barrier groups). Epilogue is
// wave-local: register argmin + ballot-prefix candidate append (no atomics).
// K-accumulation order, packed-score semantics, WWIN, CCAP identical to R5.

constexpr int Dd  = 256;
constexpr int SPB = 16384;          // 16*32*32
constexpr int Nn  = 131072;         // 8*SPB tokens
constexpr int Kk  = 1024;
constexpr int CCAP = 16;            // candidate cap per token (avg ~1.2, P(>16)~0)
#define WWIN 2.2e-3f                // collect window; >= 2x approx err + quant

typedef short short8 __attribute__((ext_vector_type(8)));
typedef float v4f    __attribute__((ext_vector_type(4)));

__device__ __forceinline__ unsigned bf16pk(float a, float b){  // RNE pack 2xbf16
  unsigned ua = __float_as_uint(a), ub = __float_as_uint(b);
  ua = (ua + 0x7fffu + ((ua >> 16) & 1u)) >> 16;
  ub = (ub + 0x7fffu + ((ub >> 16) & 1u)) & 0xffff0000u;
  return ua | ub;
}
__device__ __forceinline__ short8 frg(uint4 u){
  union { uint4 a; short8 b; } x; x.a = u; return x.b;
}
__device__ __forceinline__ v4f mfma16(short8 a, short8 b, v4f c){
  return __builtin_amdgcn_mfma_f32_16x16x32_bf16(a, b, c, 0, 0, 0);
}
__device__ __forceinline__ void dma16(const void* g, void* l){
  __builtin_amdgcn_global_load_lds((const __attribute__((address_space(1))) void*)g,
                                   (__attribute__((address_space(3))) void*)l, 16, 0, 0);
}

// ---------- prepass: ||e_k||^2 ----------
__global__ __launch_bounds__(64) void cnorm_k(const float* __restrict__ cb,
                                              float* __restrict__ cn){
  const int k = blockIdx.x, l = threadIdx.x;
  const float* row = cb + (size_t)k * Dd;
  float s = 0.f;
  #pragma unroll
  for (int c = 0; c < Dd; c += 64){ float v = row[c + l]; s += v * v; }
  #pragma unroll
  for (int off = 32; off > 0; off >>= 1) s += __shfl_down(s, off, 64);
  if (l == 0) cn[k] = s;
}

// ---------- prepass: codebook -> bf16 hi fragment plane ----------
// Bg: [cc 0..3][dc 0..7][kq 0..3][n 0..255] x 16B
__global__ __launch_bounds__(256) void cconv_k(const float* __restrict__ cb,
                                               uint4* __restrict__ Bg){
  const int cc = blockIdx.x, n = threadIdx.x;
  const float* row = cb + (size_t)(cc * 256 + n) * Dd;
  for (int dc = 0; dc < 8; dc++){
    float v[32];
    const float4* rp = (const float4*)(row + dc * 32);
    #pragma unroll
    for (int q = 0; q < 8; q++){
      float4 f = rp[q]; v[4*q]=f.x; v[4*q+1]=f.y; v[4*q+2]=f.z; v[4*q+3]=f.w;
    }
    unsigned hv[16];
    #pragma unroll
    for (int p = 0; p < 16; p++) hv[p] = bf16pk(v[2*p], v[2*p+1]);
    size_t base = ((size_t)cc * 8 + dc) * 1024;
    #pragma unroll
    for (int kq = 0; kq < 4; kq++)
      Bg[base + (size_t)kq*256 + n] = make_uint4(hv[4*kq],hv[4*kq+1],hv[4*kq+2],hv[4*kq+3]);
  }
}

// ---------- phase 1: A-in-register MFMA sweep, B double-buffered ----------
// 512 threads = 8 waves; wave w owns tokens [bId*256 + w*32, +32).
// A frags: 2 mi x 8 kk = 64 VGPR/lane, loaded once from z (f32 -> bf16 RNE).
// B: 16 chunks of 64 codes, full K=256 per chunk, 2x32KiB LDS dbuf.
// Epilogue per chunk: wave-local packed argmin + ballot-prefix collect.
__global__ __launch_bounds__(512, 4) void vq_sweep_k(const float* __restrict__ z,
                                                     const uint4* __restrict__ Bg,
                                                     const float* __restrict__ cnG,
                                                     int* __restrict__ cntW,
                                                     unsigned short* __restrict__ candW,
                                                     int* __restrict__ abestW){
  __shared__ uint4 Bs[2][2048];    // 64 KiB: [buf][dc 0..7][kq 0..3][n 0..63]
  __shared__ float cnS[1024];      // 4 KiB

  const int tid = threadIdx.x, bId = blockIdx.x;
  const int w = tid >> 6, ln = tid & 63;
  const int li = ln & 15, lq = ln >> 4;

  // ---- A: z -> bf16 frags in registers (identical bf16pk chain to zconv) ----
  const int tok0 = bId * 256;
  const int b = tok0 >> 14;                 // uniform per block
  const int s0 = tok0 & 16383;
  const float* zb = z + (size_t)b * Dd * SPB + s0;
  short8 aF[2][8];
  #pragma unroll
  for (int mi = 0; mi < 2; mi++){
    const int tl = w*32 + mi*16 + li;       // token within block
    #pragma unroll
    for (int kk = 0; kk < 8; kk++){
      float v[8];
      #pragma unroll
      for (int j = 0; j < 8; j++)
        v[j] = zb[(size_t)(kk*32 + lq*8 + j) * SPB + tl];
      union { unsigned u[4]; short8 s8; } x;
      #pragma unroll
      for (int p = 0; p < 4; p++) x.u[p] = bf16pk(v[2*p], v[2*p+1]);
      aF[mi][kk] = x.s8;
    }
  }

  // ---- stage cn (4 KiB) + B chunk 0 ----
  if (w < 4) dma16((const uint4*)cnG + w*64 + ln, (uint4*)&cnS[w*256]);
  int bOff[4];
  #pragma unroll
  for (int j = 0; j < 4; j++){
    const int f = j*512 + tid;              // [dc][kq][nl] flat
    bOff[j] = (f >> 8)*1024 + ((f >> 6) & 3)*256 + (f & 63);
  }
  #pragma unroll
  for (int j = 0; j < 4; j++)
    dma16(Bg + bOff[j], &Bs[0][j*512 + w*64]);

  unsigned bestR[8]; int cntR[8];
  #pragma unroll
  for (int i = 0; i < 8; i++){ bestR[i] = 0xFFFFFFFFu; cntR[i] = 0; }

  for (int c = 0; c < 16; c++){
    // stage chunk c+1 into the other buffer (earliest-legal point)
    if (c < 15){
      const int cn1 = c + 1;
      const size_t srcB = (size_t)(cn1 >> 2)*8192 + (size_t)((cn1 & 3)*64);
      uint4* dstB = &Bs[cn1 & 1][0];
      #pragma unroll
      for (int j = 0; j < 4; j++)
        dma16(Bg + srcB + bOff[j], dstB + j*512 + w*64);
      asm volatile("s_waitcnt vmcnt(4)" ::: "memory");   // chunk c loads done
    } else {
      asm volatile("s_waitcnt vmcnt(0)" ::: "memory");
    }
    __builtin_amdgcn_s_barrier();
    asm volatile("" ::: "memory");

    v4f acc[2][4];
    const v4f vz = {0.f, 0.f, 0.f, 0.f};
    #pragma unroll
    for (int mi = 0; mi < 2; mi++)
      #pragma unroll
      for (int ni = 0; ni < 4; ni++) acc[mi][ni] = vz;

    const uint4* Bbase = &Bs[c & 1][lq*64 + li];
    __builtin_amdgcn_s_setprio(1);
    #pragma unroll
    for (int kk = 0; kk < 8; kk++){           // dc ascending: same K-order as R5
      short8 b0 = frg(Bbase[kk*256 +  0]);
      short8 b1 = frg(Bbase[kk*256 + 16]);
      short8 b2 = frg(Bbase[kk*256 + 32]);
      short8 b3 = frg(Bbase[kk*256 + 48]);
      #pragma unroll
      for (int mi = 0; mi < 2; mi++){
        acc[mi][0] = mfma16(aF[mi][kk], b0, acc[mi][0]);
        acc[mi][1] = mfma16(aF[mi][kk], b1, acc[mi][1]);
        acc[mi][2] = mfma16(aF[mi][kk], b2, acc[mi][2]);
        acc[mi][3] = mfma16(aF[mi][kk], b3, acc[mi][3]);
      }
    }
    __builtin_amdgcn_s_setprio(0);

    float cnv[4];
    #pragma unroll
    for (int ni = 0; ni < 4; ni++) cnv[ni] = cnS[c*64 + ni*16 + li];

    // ---- wave-local epilogue: pack, reduce over li, collect (no barriers) ----
    const int codeB = c*64 + li;
    #pragma unroll
    for (int mi = 0; mi < 2; mi++){
      #pragma unroll
      for (int r = 0; r < 4; r++){
        const int i = mi*4 + r;
        unsigned pm = 0xFFFFFFFFu;
        #pragma unroll
        for (int ni = 0; ni < 4; ni++){
          float s = fmaf(acc[mi][ni][r], -2.0f, cnv[ni]);      // zn cancels
          unsigned u = __float_as_uint(s);
          u ^= (unsigned)((int)u >> 31) | 0x80000000u;          // sortable uint
          unsigned p = (u & 0xFFFFFC00u) | (unsigned)(codeB + ni*16);
          acc[mi][ni][r] = __uint_as_float(p);                  // stash
          pm = (pm < p) ? pm : p;
        }
        unsigned pmw = pm;
        #pragma unroll
        for (int off = 1; off < 16; off <<= 1){
          unsigned o = (unsigned)__shfl_xor((int)pmw, off, 16);
          pmw = (pmw < o) ? pmw : o;
        }
        bestR[i] = (bestR[i] < pmw) ? bestR[i] : pmw;
        // packed threshold (same unpack/repack as R5)
        unsigned bp = bestR[i] & 0xFFFFFC00u;
        unsigned fb = (bp & 0x80000000u) ? (bp ^ 0x80000000u) : ~bp;
        float thrf = __uint_as_float(fb) + WWIN;
        unsigned tu = __float_as_uint(thrf);
        tu ^= (unsigned)((int)tu >> 31) | 0x80000000u;
        tu |= 1023u;
        if (__any(pm <= tu)){                   // uniform fast-skip
          const int tok = tok0 + w*32 + mi*16 + lq*4 + r;
          int base = cntR[i];
          #pragma unroll
          for (int ni = 0; ni < 4; ni++){
            const unsigned p = __float_as_uint(acc[mi][ni][r]);
            const bool pass = (p <= tu);
            unsigned long long bal = __ballot(pass);
            const unsigned bq = (unsigned)(bal >> (lq*16)) & 0xFFFFu;
            if (pass){
              int pos = base + __popc(bq & ((1u << li) - 1u));
              if (pos < CCAP)
                candW[(size_t)tok*CCAP + pos] = (unsigned short)(p & 1023u);
            }
            base += __popc(bq);
          }
          cntR[i] = base;
        }
      }
    }
    __builtin_amdgcn_s_barrier();      // reads of buf[c&1] done -> reusable
    asm volatile("" ::: "memory");
  }

  // ---- final dump (registers only) ----
  if (li == 0){
    #pragma unroll
    for (int mi = 0; mi < 2; mi++)
      #pragma unroll
      for (int r = 0; r < 4; r++){
        const int i = mi*4 + r;
        const int tok = tok0 + w*32 + mi*16 + lq*4 + r;
        cntW[tok] = cntR[i];
        abestW[tok] = (int)(bestR[i] & 1023u);
      }
  }
}

// ---------- phase 2: exact fp32 rescore (R3-proven arithmetic), 1 thread/token ----------
__global__ __launch_bounds__(256) void vq_rescore_k(const float* __restrict__ z,
                                                    const float* __restrict__ cb,
                                                    const float* __restrict__ cnG,
                                                    const int* __restrict__ cntW,
                                                    const unsigned short* __restrict__ candW,
                                                    const int* __restrict__ abestW,
                                                    int* __restrict__ idsW,
                                                    float* __restrict__ out){
  const int tok = blockIdx.x * 256 + threadIdx.x;
  const int b = tok >> 14, s = tok & 16383;
  const float* zr = z + (size_t)b * Dd * SPB + s;

  int n = cntW[tok];
  const bool ovf = (n > CCAP);
  if (ovf) n = CCAP;
  unsigned short cds[CCAP];
  *(uint4*)&cds[0] = *(const uint4*)&candW[(size_t)tok * CCAP];
  *(uint4*)&cds[8] = *(const uint4*)&candW[(size_t)tok * CCAP + 8];

  float bv = 3.4e38f; int bi = 0x7fffffff;
  float znl = 0.f;
  const int ngroups = (n + 3) >> 2;
  const int total = ovf ? ngroups + 1 : ngroups;

  for (int g = 0; g < total; g++){
    int idxs[4];
    #pragma unroll
    for (int ss = 0; ss < 4; ss++){
      int slot = g*4 + ss; if (slot >= n) slot = n - 1;
      idxs[ss] = (g < ngroups) ? (int)cds[slot] : abestW[tok];
    }
    const float* cr0 = cb + (size_t)idxs[0] * Dd;
    const float* cr1 = cb + (size_t)idxs[1] * Dd;
    const float* cr2 = cb + (size_t)idxs[2] * Dd;
    const float* cr3 = cb + (size_t)idxs[3] * Dd;
    float a0=0.f, a1=0.f, a2=0.f, a3=0.f, za=0.f;
    for (int d = 0; d < Dd; d += 8){
      float zv[8];
      #pragma unroll
      for (int j = 0; j < 8; j++) zv[j] = zr[(size_t)(d + j) * SPB];
      float4 c0a = *(const float4*)(cr0 + d), c0b = *(const float4*)(cr0 + d + 4);
      float4 c1a = *(const float4*)(cr1 + d), c1b = *(const float4*)(cr1 + d + 4);
      float4 c2a = *(const float4*)(cr2 + d), c2b = *(const float4*)(cr2 + d + 4);
      float4 c3a = *(const float4*)(cr3 + d), c3b = *(const float4*)(cr3 + d + 4);
      float cv0[8] = {c0a.x,c0a.y,c0a.z,c0a.w,c0b.x,c0b.y,c0b.z,c0b.w};
      float cv1[8] = {c1a.x,c1a.y,c1a.z,c1a.w,c1b.x,c1b.y,c1b.z,c1b.w};
      float cv2[8] = {c2a.x,c2a.y,c2a.z,c2a.w,c2b.x,c2b.y,c2b.z,c2b.w};
      float cv3[8] = {c3a.x,c3a.y,c3a.z,c3a.w,c3b.x,c3b.y,c3b.z,c3b.w};
      #pragma unroll
      for (int j = 0; j < 8; j++){
        if (g == 0) za = fmaf(zv[j], zv[j], za);
        a0 = fmaf(zv[j], cv0[j], a0);
        a1 = fmaf(zv[j], cv1[j], a1);
        a2 = fmaf(zv[j], cv2[j], a2);
        a3 = fmaf(zv[j], cv3[j], a3);
      }
    }
    if (g == 0) znl = za;
    float av[4] = {a0, a1, a2, a3};
    const int lim = (g < ngroups) ? n : 1;
    #pragma unroll
    for (int ss = 0; ss < 4; ss++){
      if (g*4 + ss < lim || (g >= ngroups && ss == 0)){
        float t  = znl - 2.0f * av[ss];
        float d2 = t + cnG[idxs[ss]];
        if (d2 < bv || (d2 == bv && idxs[ss] < bi)){ bv = d2; bi = idxs[ss]; }
      }
    }
  }
  idsW[tok] = bi;
  out[(size_t)2 * Nn * Dd + tok] = (float)bi;
}

// ---------- phase 3: LDS-transpose gather ----------
__global__ __launch_bounds__(256) void vq_gather_k(const float* __restrict__ cb,
                                                   const int* __restrict__ idsW,
                                                   float* __restrict__ out){
  __shared__ float tile[64][129];
  __shared__ int lid[64];
  const int tid = threadIdx.x, blk = blockIdx.x;   // 2048 blocks
  const int b = blk >> 8, s0 = (blk & 255) * 64;
  if (tid < 64) lid[tid] = idsW[b * SPB + s0 + tid];
  __syncthreads();

  const int r2 = tid >> 7, c = tid & 127;          // load mapping
  const int s = tid & 63, cq = tid >> 6;           // store mapping
  float* qb  = out + (size_t)b * Dd * SPB + s0 + s;
  float* stb = qb + (size_t)Nn * Dd;

  for (int ch = 0; ch < 2; ch++){
    #pragma unroll 4
    for (int t0 = 0; t0 < 64; t0 += 2){
      const int row = t0 + r2;
      tile[row][c] = cb[(size_t)lid[row] * Dd + ch*128 + c];
    }
    __syncthreads();
    #pragma unroll 8
    for (int i = 0; i < 32; i++){
      const int cc2 = i*4 + cq;
      const float v = tile[s][cc2];
      const size_t off = (size_t)(ch*128 + cc2) * SPB;
      qb[off]  = v;
      stb[off] = v;
    }
    __syncthreads();
  }
}

// ================= R1 fp32 fallback (used if ws too small) =================
#define MICRO_STEP(WITH_ZN)                                                    \
    {                                                                          \
        float4 a0 = *(const float4*)&As[d][ty * 8];                            \
        float4 a1 = *(const float4*)&As[d][ty * 8 + 4];                        \
        float4 b0 = *(const float4*)&Bs[d][tx * 8];                            \
        float4 b1 = *(const float4*)&Bs[d][tx * 8 + 4];                        \
        float a[8] = {a0.x, a0.y, a0.z, a0.w, a1.x, a1.y, a1.z, a1.w};         \
        float bb[8] = {b0.x, b0.y, b0.z, b0.w, b1.x, b1.y, b1.z, b1.w};        \
        _Pragma("unroll")                                                      \
        for (int i = 0; i < 8; i++) {                                          \
            _Pragma("unroll")                                                  \
            for (int j = 0; j < 8; j++) acc[i][j] += a[i] * bb[j];             \
            if (WITH_ZN) zn[i] += a[i] * a[i];                                 \
        }                                                                      \
    }

__global__ __launch_bounds__(256) void vq_k(const float* __restrict__ z,
                                            const float* __restrict__ cb,
                                            const float* __restrict__ cn,
                                            float* __restrict__ out){
  __shared__ float As[16][128];
  __shared__ float Bs[16][132];
  __shared__ int   idsf[128];
  const int tid = threadIdx.x;
  const int tx = tid & 15, ty = tid >> 4;
  const int blk = blockIdx.x;
  const int b = blk >> 7, sb = (blk & 127) * 128;
  const float* zb = z + (size_t)b * Dd * SPB + sb;
  float bestv[8]; int besti[8]; float zn[8];
  #pragma unroll
  for (int i = 0; i < 8; i++){ bestv[i] = 3.4e38f; besti[i] = 0; zn[i] = 0.f; }
  const int am = tid & 127, ad = tid >> 7;
  const int bd = tid & 15,  bk = tid >> 4;
  for (int cc = 0; cc < 8; cc++){
    float acc[8][8];
    #pragma unroll
    for (int i = 0; i < 8; i++)
      #pragma unroll
      for (int j = 0; j < 8; j++) acc[i][j] = 0.f;
    for (int dc = 0; dc < 16; dc++){
      #pragma unroll
      for (int r = 0; r < 8; r++){
        const int d = ad + r * 2;
        As[d][am] = zb[(size_t)(dc*16 + d) * SPB + am];
      }
      #pragma unroll
      for (int r = 0; r < 8; r++){
        const int k = bk + r * 16;
        Bs[bd][k] = cb[(size_t)(cc*128 + k) * Dd + dc*16 + bd];
      }
      __syncthreads();
      if (cc == 0){
        #pragma unroll
        for (int d = 0; d < 16; d++) MICRO_STEP(1)
      } else {
        #pragma unroll
        for (int d = 0; d < 16; d++) MICRO_STEP(0)
      }
      __syncthreads();
    }
    const float* cnp = cn + cc*128 + tx*8;
    float4 c0 = *(const float4*)cnp;
    float4 c1 = *(const float4*)(cnp + 4);
    float cv[8] = {c0.x, c0.y, c0.z, c0.w, c1.x, c1.y, c1.z, c1.w};
    #pragma unroll
    for (int i = 0; i < 8; i++){
      #pragma unroll
      for (int j = 0; j < 8; j++){
        float t  = zn[i] - 2.0f * acc[i][j];
        float d2 = t + cv[j];
        int   ix = cc*128 + tx*8 + j;
        if (d2 < bestv[i]){ bestv[i] = d2; besti[i] = ix; }
      }
    }
  }
  #pragma unroll
  for (int i = 0; i < 8; i++){
    float v = bestv[i]; int ix = besti[i];
    #pragma unroll
    for (int off = 8; off > 0; off >>= 1){
      float ov = __shfl_down(v, off, 16);
      int   oi = __shfl_down(ix, off, 16);
      if (ov < v || (ov == v && oi < ix)){ v = ov; ix = oi; }
    }
    if (tx == 0) idsf[ty*8 + i] = ix;
  }
  __syncthreads();
  if (tid < 128) out[(size_t)2*Nn*Dd + (size_t)blk*128 + tid] = (float)idsf[tid];
  const int m = tid & 127, cg = tid >> 7;
  const int myidx = idsf[m];
  const float* crow = cb + (size_t)myidx * Dd + cg*128;
  float* q  = out + (size_t)b * Dd * SPB + (size_t)cg * 128 * SPB + sb + m;
  float* st = q + (size_t)Nn * Dd;
  #pragma unroll 8
  for (int r = 0; r < 128; r++){
    const float v = crow[r];
    q[(size_t)r * SPB]  = v;
    st[(size_t)r * SPB] = v;
  }
}

// ---------- launcher ----------
extern "C" void kernel_launch(void* const* d_in, const int* in_sizes, int n_in,
                              void* d_out, int out_size, void* d_ws, size_t ws_size,
                              hipStream_t stream){
  const float* z  = (const float*)d_in[0];
  const float* cb = (const float*)d_in[1];
  float* out = (float*)d_out;

  const size_t BG_B  = (size_t)4 * 8 * 1024 * 16;     // 512 KiB
  const size_t CN_B  = (size_t)Kk * 4;                // 4 KiB
  const size_t CNT_B = (size_t)Nn * 4;                // 512 KiB
  const size_t CAN_B = (size_t)Nn * CCAP * 2;         // 4 MiB
  const size_t ABW_B = (size_t)Nn * 4;                // 512 KiB
  const size_t IDS_B = (size_t)Nn * 4;                // 512 KiB
  const size_t NEED = BG_B + CN_B + CNT_B + CAN_B + ABW_B + IDS_B;

  if (ws_size >= NEED){
    uint8_t* ws = (uint8_t*)d_ws;
    size_t o = 0;
    uint4* Bg   = (uint4*)(ws + o);          o += BG_B;
    float* cnG  = (float*)(ws + o);          o += CN_B;
    int*   cntW = (int*)(ws + o);            o += CNT_B;
    unsigned short* candW = (unsigned short*)(ws + o); o += CAN_B;
    int*   abW  = (int*)(ws + o);            o += ABW_B;
    int*   idsW = (int*)(ws + o);            o += IDS_B;

    cnorm_k<<<Kk, 64, 0, stream>>>(cb, cnG);
    cconv_k<<<4, 256, 0, stream>>>(cb, Bg);
    vq_sweep_k<<<Nn/256, 512, 0, stream>>>(z, Bg, cnG, cntW, candW, abW);
    vq_rescore_k<<<Nn/256, 256, 0, stream>>>(z, cb, cnG, cntW, candW, abW, idsW, out);
    vq_gather_k<<<Nn/64, 256, 0, stream>>>(cb, idsW, out);
  } else {
    float* cn = (float*)d_ws;
    cnorm_k<<<Kk, 64, 0, stream>>>(cb, cn);
    vq_k<<<Nn/128, 256, 0, stream>>>(z, cb, cn, out);
  }
}

// Round 3
// 687.204 us; speedup vs baseline: 1.1446x; 1.0444x over previous
//
#include <hip/hip_runtime.h>
#include <stdint.h>

// VQ-VAE codebook quantize: z (8,256,16,32,32) f32, codebook (1024,256) f32.
// Outputs (concat in d_out, f32): quantized, st (== quantized fwd), indices.
// R7: spill elimination + light-token fast path.
//  - sweep: wave owns 16 tokens (live regs ~85 < 128 cap -> no scratch; R6's
//    VGPR=64 + FETCH/WRITE anomalies were spill traffic). B double-buffer,
//    counted vmcnt, raw barriers, setprio kept (R6-proven protocol).
//  - cnt==1 tokens are finalized IN the sweep (the lone candidate == running
//    best == true argmin, by the window guarantee); heavy tokens (~20%) are
//    block-compacted into heavyList; rescore grid-strides over that list at
//    full lane density. Exact-rescore body unchanged.

constexpr int Dd  = 256;
constexpr int SPB = 16384;          // 16*32*32
constexpr int Nn  = 131072;         // 8*SPB tokens
constexpr int Kk  = 1024;
constexpr int CCAP = 16;            // candidate cap per token (avg ~1.2, P(>16)~0)
#define WWIN 2.2e-3f                // collect window; >= 2x approx err + quant

typedef short short8 __attribute__((ext_vector_type(8)));
typedef float v4f    __attribute__((ext_vector_type(4)));

__device__ __forceinline__ unsigned bf16pk(float a, float b){  // RNE pack 2xbf16
  unsigned ua = __float_as_uint(a), ub = __float_as_uint(b);
  ua = (ua + 0x7fffu + ((ua >> 16) & 1u)) >> 16;
  ub = (ub + 0x7fffu + ((ub >> 16) & 1u)) & 0xffff0000u;
  return ua | ub;
}
__device__ __forceinline__ short8 frg(uint4 u){
  union { uint4 a; short8 b; } x; x.a = u; return x.b;
}
__device__ __forceinline__ v4f mfma16(short8 a, short8 b, v4f c){
  return __builtin_amdgcn_mfma_f32_16x16x32_bf16(a, b, c, 0, 0, 0);
}
__device__ __forceinline__ void dma16(const void* g, void* l){
  __builtin_amdgcn_global_load_lds((const __attribute__((address_space(1))) void*)g,
                                   (__attribute__((address_space(3))) void*)l, 16, 0, 0);
}

// ---------- prepass: ||e_k||^2 (also zeroes heavyCnt) ----------
__global__ __launch_bounds__(64) void cnorm_k(const float* __restrict__ cb,
                                              float* __restrict__ cn,
                                              int* __restrict__ heavyCnt){
  const int k = blockIdx.x, l = threadIdx.x;
  if (k == 0 && l == 0) heavyCnt[0] = 0;
  const float* row = cb + (size_t)k * Dd;
  float s = 0.f;
  #pragma unroll
  for (int c = 0; c < Dd; c += 64){ float v = row[c + l]; s += v * v; }
  #pragma unroll
  for (int off = 32; off > 0; off >>= 1) s += __shfl_down(s, off, 64);
  if (l == 0) cn[k] = s;
}

// ---------- prepass: codebook -> bf16 hi fragment plane ----------
// Bg: [cc 0..3][dc 0..7][kq 0..3][n 0..255] x 16B
__global__ __launch_bounds__(256) void cconv_k(const float* __restrict__ cb,
                                               uint4* __restrict__ Bg){
  const int cc = blockIdx.x, n = threadIdx.x;
  const float* row = cb + (size_t)(cc * 256 + n) * Dd;
  for (int dc = 0; dc < 8; dc++){
    float v[32];
    const float4* rp = (const float4*)(row + dc * 32);
    #pragma unroll
    for (int q = 0; q < 8; q++){
      float4 f = rp[q]; v[4*q]=f.x; v[4*q+1]=f.y; v[4*q+2]=f.z; v[4*q+3]=f.w;
    }
    unsigned hv[16];
    #pragma unroll
    for (int p = 0; p < 16; p++) hv[p] = bf16pk(v[2*p], v[2*p+1]);
    size_t base = ((size_t)cc * 8 + dc) * 1024;
    #pragma unroll
    for (int kq = 0; kq < 4; kq++)
      Bg[base + (size_t)kq*256 + n] = make_uint4(hv[4*kq],hv[4*kq+1],hv[4*kq+2],hv[4*kq+3]);
  }
}

// ---------- phase 1: A-in-register MFMA sweep (16 tokens/wave, spill-free) ----
// 512 threads = 8 waves; wave w owns tokens [bId*128 + w*16, +16).
// A frags: 8 kk = 32 VGPR/lane. B: 16 chunks of 64 codes, 2x32KiB LDS dbuf.
// Light tokens (cnt==1) finalized here; heavy tokens block-compacted.
__global__ __launch_bounds__(512, 4) void vq_sweep_k(const float* __restrict__ z,
                                                     const uint4* __restrict__ Bg,
                                                     const float* __restrict__ cnG,
                                                     int* __restrict__ cntW,
                                                     unsigned short* __restrict__ candW,
                                                     int* __restrict__ abestW,
                                                     int* __restrict__ heavyCnt,
                                                     int* __restrict__ heavyList,
                                                     int* __restrict__ idsW,
                                                     float* __restrict__ out){
  __shared__ uint4 Bs[2][2048];    // 64 KiB: [buf][dc 0..7][kq 0..3][n 0..63]
  __shared__ float cnS[1024];      // 4 KiB
  __shared__ int hN;
  __shared__ int gBase;
  __shared__ int hT[128];

  const int tid = threadIdx.x, bId = blockIdx.x;
  const int w = tid >> 6, ln = tid & 63;
  const int li = ln & 15, lq = ln >> 4;

  if (tid == 0) hN = 0;

  // ---- stage cn (4 KiB) + B chunk 0 first (overlaps the A-load below) ----
  if (w < 4) dma16((const uint4*)cnG + w*64 + ln, (uint4*)&cnS[w*256]);
  int bOff[4];
  #pragma unroll
  for (int j = 0; j < 4; j++){
    const int f = j*512 + tid;              // [dc][kq][nl] flat
    bOff[j] = (f >> 8)*1024 + ((f >> 6) & 3)*256 + (f & 63);
  }
  #pragma unroll
  for (int j = 0; j < 4; j++)
    dma16(Bg + bOff[j], &Bs[0][j*512 + w*64]);

  // ---- A: z -> bf16 frags in registers (verified bf16pk chain) ----
  const int tok0 = bId * 128;
  const int b = tok0 >> 14;                 // uniform per block
  const int s0 = tok0 & 16383;
  const float* zb = z + (size_t)b * Dd * SPB + s0;
  short8 aF[8];
  const int tl = w*16 + li;                 // token within block (A-frag row)
  #pragma unroll
  for (int kk = 0; kk < 8; kk++){
    float v[8];
    #pragma unroll
    for (int j = 0; j < 8; j++)
      v[j] = zb[(size_t)(kk*32 + lq*8 + j) * SPB + tl];
    union { unsigned u[4]; short8 s8; } x;
    #pragma unroll
    for (int p = 0; p < 4; p++) x.u[p] = bf16pk(v[2*p], v[2*p+1]);
    aF[kk] = x.s8;
  }

  unsigned bestR[4], thrU[4]; int cntR[4];
  #pragma unroll
  for (int i = 0; i < 4; i++){ bestR[i] = 0xFFFFFFFFu; thrU[i] = 0u; cntR[i] = 0; }

  for (int c = 0; c < 16; c++){
    // stage chunk c+1 into the other buffer
    if (c < 15){
      const int cn1 = c + 1;
      const int srcB = (cn1 >> 2)*8192 + (cn1 & 3)*64;
      uint4* dstB = &Bs[cn1 & 1][0];
      #pragma unroll
      for (int j = 0; j < 4; j++)
        dma16(Bg + srcB + bOff[j], dstB + j*512 + w*64);
      asm volatile("s_waitcnt vmcnt(4)" ::: "memory");   // chunk c loads done
    } else {
      asm volatile("s_waitcnt vmcnt(0)" ::: "memory");
    }
    __builtin_amdgcn_s_barrier();
    asm volatile("" ::: "memory");

    v4f acc[4];
    const v4f vz = {0.f, 0.f, 0.f, 0.f};
    #pragma unroll
    for (int ni = 0; ni < 4; ni++) acc[ni] = vz;

    const uint4* Bbase = &Bs[c & 1][lq*64 + li];
    __builtin_amdgcn_s_setprio(1);
    #pragma unroll
    for (int kk = 0; kk < 8; kk++){           // dc ascending: same K-order
      short8 b0 = frg(Bbase[kk*256 +  0]);
      short8 b1 = frg(Bbase[kk*256 + 16]);
      short8 b2 = frg(Bbase[kk*256 + 32]);
      short8 b3 = frg(Bbase[kk*256 + 48]);
      acc[0] = mfma16(aF[kk], b0, acc[0]);
      acc[1] = mfma16(aF[kk], b1, acc[1]);
      acc[2] = mfma16(aF[kk], b2, acc[2]);
      acc[3] = mfma16(aF[kk], b3, acc[3]);
    }
    __builtin_amdgcn_s_setprio(0);

    float cnv[4];
    #pragma unroll
    for (int ni = 0; ni < 4; ni++) cnv[ni] = cnS[c*64 + ni*16 + li];

    // ---- wave-local epilogue: pack, reduce over li, collect ----
    const int codeB = c*64 + li;
    #pragma unroll
    for (int r = 0; r < 4; r++){
      unsigned pv[4];
      unsigned pm = 0xFFFFFFFFu;
      #pragma unroll
      for (int ni = 0; ni < 4; ni++){
        float s = fmaf(acc[ni][r], -2.0f, cnv[ni]);          // zn cancels
        unsigned u = __float_as_uint(s);
        u ^= (unsigned)((int)u >> 31) | 0x80000000u;          // sortable uint
        unsigned p = (u & 0xFFFFFC00u) | (unsigned)(codeB + ni*16);
        pv[ni] = p;
        pm = (pm < p) ? pm : p;
      }
      unsigned pmw = pm;
      #pragma unroll
      for (int off = 1; off < 16; off <<= 1){
        unsigned o = (unsigned)__shfl_xor((int)pmw, off, 16);
        pmw = (pmw < o) ? pmw : o;
      }
      if (pmw <= bestR[r]){                   // always true at c==0
        bestR[r] = pmw;
        unsigned bp = pmw & 0xFFFFFC00u;
        unsigned fb = (bp & 0x80000000u) ? (bp ^ 0x80000000u) : ~bp;
        float thrf = __uint_as_float(fb) + WWIN;
        unsigned tu = __float_as_uint(thrf);
        tu ^= (unsigned)((int)tu >> 31) | 0x80000000u;
        thrU[r] = tu | 1023u;                 // inclusive of code bits
      }
      if (__any(pm <= thrU[r])){              // fast-skip most chunks
        const int tok = tok0 + w*16 + lq*4 + r;
        int base = cntR[r];
        #pragma unroll
        for (int ni = 0; ni < 4; ni++){
          const unsigned p = pv[ni];
          const bool pass = (p <= thrU[r]);
          unsigned long long bal = __ballot(pass);
          const unsigned bq = (unsigned)(bal >> (lq*16)) & 0xFFFFu;
          if (pass){
            int pos = base + __popc(bq & ((1u << li) - 1u));
            if (pos < CCAP)
              candW[(size_t)tok*CCAP + pos] = (unsigned short)(p & 1023u);
          }
          base += __popc(bq);
        }
        cntR[r] = base;
      }
    }
    __builtin_amdgcn_s_barrier();      // reads of buf[c&1] done -> reusable
    asm volatile("" ::: "memory");
  }

  // ---- final dump: light tokens finalized, heavy tokens compacted ----
  if (li == 0){
    #pragma unroll
    for (int r = 0; r < 4; r++){
      const int tok = tok0 + w*16 + lq*4 + r;
      if (cntR[r] == 1){
        const int code = (int)(bestR[r] & 1023u);
        idsW[tok] = code;
        out[(size_t)2 * Nn * Dd + tok] = (float)code;
      } else {
        int p = atomicAdd(&hN, 1);
        hT[p] = tok;
        cntW[tok] = cntR[r];
        abestW[tok] = (int)(bestR[r] & 1023u);
      }
    }
  }
  __syncthreads();
  if (tid == 0) gBase = hN ? atomicAdd(heavyCnt, hN) : 0;
  __syncthreads();
  if (tid < hN) heavyList[gBase + tid] = hT[tid];
}

// ---------- phase 2: exact fp32 rescore over heavy tokens only ----------
__global__ __launch_bounds__(256) void vq_rescore_k(const float* __restrict__ z,
                                                    const float* __restrict__ cb,
                                                    const float* __restrict__ cnG,
                                                    const int* __restrict__ cntW,
                                                    const unsigned short* __restrict__ candW,
                                                    const int* __restrict__ abestW,
                                                    const int* __restrict__ heavyCnt,
                                                    const int* __restrict__ heavyList,
                                                    int* __restrict__ idsW,
                                                    float* __restrict__ out){
  const int hc = heavyCnt[0];
  for (int i = blockIdx.x * 256 + threadIdx.x; i < hc; i += gridDim.x * 256){
    const int tok = heavyList[i];
    const int b = tok >> 14, s = tok & 16383;
    const float* zr = z + (size_t)b * Dd * SPB + s;

    int n = cntW[tok];
    const bool ovf = (n > CCAP);
    if (ovf) n = CCAP;
    unsigned short cds[CCAP];
    *(uint4*)&cds[0] = *(const uint4*)&candW[(size_t)tok * CCAP];
    *(uint4*)&cds[8] = *(const uint4*)&candW[(size_t)tok * CCAP + 8];

    float bv = 3.4e38f; int bi = 0x7fffffff;
    float znl = 0.f;
    const int ngroups = (n + 3) >> 2;
    const int total = ovf ? ngroups + 1 : ngroups;

    for (int g = 0; g < total; g++){
      int idxs[4];
      #pragma unroll
      for (int ss = 0; ss < 4; ss++){
        int slot = g*4 + ss; if (slot >= n) slot = n - 1;
        idxs[ss] = (g < ngroups) ? (int)cds[slot] : abestW[tok];
      }
      const float* cr0 = cb + (size_t)idxs[0] * Dd;
      const float* cr1 = cb + (size_t)idxs[1] * Dd;
      const float* cr2 = cb + (size_t)idxs[2] * Dd;
      const float* cr3 = cb + (size_t)idxs[3] * Dd;
      float a0=0.f, a1=0.f, a2=0.f, a3=0.f, za=0.f;
      for (int d = 0; d < Dd; d += 8){
        float zv[8];
        #pragma unroll
        for (int j = 0; j < 8; j++) zv[j] = zr[(size_t)(d + j) * SPB];
        float4 c0a = *(const float4*)(cr0 + d), c0b = *(const float4*)(cr0 + d + 4);
        float4 c1a = *(const float4*)(cr1 + d), c1b = *(const float4*)(cr1 + d + 4);
        float4 c2a = *(const float4*)(cr2 + d), c2b = *(const float4*)(cr2 + d + 4);
        float4 c3a = *(const float4*)(cr3 + d), c3b = *(const float4*)(cr3 + d + 4);
        float cv0[8] = {c0a.x,c0a.y,c0a.z,c0a.w,c0b.x,c0b.y,c0b.z,c0b.w};
        float cv1[8] = {c1a.x,c1a.y,c1a.z,c1a.w,c1b.x,c1b.y,c1b.z,c1b.w};
        float cv2[8] = {c2a.x,c2a.y,c2a.z,c2a.w,c2b.x,c2b.y,c2b.z,c2b.w};
        float cv3[8] = {c3a.x,c3a.y,c3a.z,c3a.w,c3b.x,c3b.y,c3b.z,c3b.w};
        #pragma unroll
        for (int j = 0; j < 8; j++){
          if (g == 0) za = fmaf(zv[j], zv[j], za);
          a0 = fmaf(zv[j], cv0[j], a0);
          a1 = fmaf(zv[j], cv1[j], a1);
          a2 = fmaf(zv[j], cv2[j], a2);
          a3 = fmaf(zv[j], cv3[j], a3);
        }
      }
      if (g == 0) znl = za;
      float av[4] = {a0, a1, a2, a3};
      const int lim = (g < ngroups) ? n : 1;
      #pragma unroll
      for (int ss = 0; ss < 4; ss++){
        if (g*4 + ss < lim || (g >= ngroups && ss == 0)){
          float t  = znl - 2.0f * av[ss];
          float d2 = t + cnG[idxs[ss]];
          if (d2 < bv || (d2 == bv && idxs[ss] < bi)){ bv = d2; bi = idxs[ss]; }
        }
      }
    }
    idsW[tok] = bi;
    out[(size_t)2 * Nn * Dd + tok] = (float)bi;
  }
}

// ---------- phase 3: LDS-transpose gather ----------
__global__ __launch_bounds__(256) void vq_gather_k(const float* __restrict__ cb,
                                                   const int* __restrict__ idsW,
                                                   float* __restrict__ out){
  __shared__ float tile[64][129];
  __shared__ int lid[64];
  const int tid = threadIdx.x, blk = blockIdx.x;   // 2048 blocks
  const int b = blk >> 8, s0 = (blk & 255) * 64;
  if (tid < 64) lid[tid] = idsW[b * SPB + s0 + tid];
  __syncthreads();

  const int r2 = tid >> 7, c = tid & 127;          // load mapping
  const int s = tid & 63, cq = tid >> 6;           // store mapping
  float* qb  = out + (size_t)b * Dd * SPB + s0 + s;
  float* stb = qb + (size_t)Nn * Dd;

  for (int ch = 0; ch < 2; ch++){
    #pragma unroll 4
    for (int t0 = 0; t0 < 64; t0 += 2){
      const int row = t0 + r2;
      tile[row][c] = cb[(size_t)lid[row] * Dd + ch*128 + c];
    }
    __syncthreads();
    #pragma unroll 8
    for (int i = 0; i < 32; i++){
      const int cc2 = i*4 + cq;
      const float v = tile[s][cc2];
      const size_t off = (size_t)(ch*128 + cc2) * SPB;
      qb[off]  = v;
      stb[off] = v;
    }
    __syncthreads();
  }
}

// ================= R1 fp32 fallback (used if ws too small) =================
#define MICRO_STEP(WITH_ZN)                                                    \
    {                                                                          \
        float4 a0 = *(const float4*)&As[d][ty * 8];                            \
        float4 a1 = *(const float4*)&As[d][ty * 8 + 4];                        \
        float4 b0 = *(const float4*)&Bs[d][tx * 8];                            \
        float4 b1 = *(const float4*)&Bs[d][tx * 8 + 4];                        \
        float a[8] = {a0.x, a0.y, a0.z, a0.w, a1.x, a1.y, a1.z, a1.w};         \
        float bb[8] = {b0.x, b0.y, b0.z, b0.w, b1.x, b1.y, b1.z, b1.w};        \
        _Pragma("unroll")                                                      \
        for (int i = 0; i < 8; i++) {                                          \
            _Pragma("unroll")                                                  \
            for (int j = 0; j < 8; j++) acc[i][j] += a[i] * bb[j];             \
            if (WITH_ZN) zn[i] += a[i] * a[i];                                 \
        }                                                                      \
    }

__global__ __launch_bounds__(256) void vq_k(const float* __restrict__ z,
                                            const float* __restrict__ cb,
                                            const float* __restrict__ cn,
                                            float* __restrict__ out){
  __shared__ float As[16][128];
  __shared__ float Bs[16][132];
  __shared__ int   idsf[128];
  const int tid = threadIdx.x;
  const int tx = tid & 15, ty = tid >> 4;
  const int blk = blockIdx.x;
  const int b = blk >> 7, sb = (blk & 127) * 128;
  const float* zb = z + (size_t)b * Dd * SPB + sb;
  float bestv[8]; int besti[8]; float zn[8];
  #pragma unroll
  for (int i = 0; i < 8; i++){ bestv[i] = 3.4e38f; besti[i] = 0; zn[i] = 0.f; }
  const int am = tid & 127, ad = tid >> 7;
  const int bd = tid & 15,  bk = tid >> 4;
  for (int cc = 0; cc < 8; cc++){
    float acc[8][8];
    #pragma unroll
    for (int i = 0; i < 8; i++)
      #pragma unroll
      for (int j = 0; j < 8; j++) acc[i][j] = 0.f;
    for (int dc = 0; dc < 16; dc++){
      #pragma unroll
      for (int r = 0; r < 8; r++){
        const int d = ad + r * 2;
        As[d][am] = zb[(size_t)(dc*16 + d) * SPB + am];
      }
      #pragma unroll
      for (int r = 0; r < 8; r++){
        const int k = bk + r * 16;
        Bs[bd][k] = cb[(size_t)(cc*128 + k) * Dd + dc*16 + bd];
      }
      __syncthreads();
      if (cc == 0){
        #pragma unroll
        for (int d = 0; d < 16; d++) MICRO_STEP(1)
      } else {
        #pragma unroll
        for (int d = 0; d < 16; d++) MICRO_STEP(0)
      }
      __syncthreads();
    }
    const float* cnp = cn + cc*128 + tx*8;
    float4 c0 = *(const float4*)cnp;
    float4 c1 = *(const float4*)(cnp + 4);
    float cv[8] = {c0.x, c0.y, c0.z, c0.w, c1.x, c1.y, c1.z, c1.w};
    #pragma unroll
    for (int i = 0; i < 8; i++){
      #pragma unroll
      for (int j = 0; j < 8; j++){
        float t  = zn[i] - 2.0f * acc[i][j];
        float d2 = t + cv[j];
        int   ix = cc*128 + tx*8 + j;
        if (d2 < bestv[i]){ bestv[i] = d2; besti[i] = ix; }
      }
    }
  }
  #pragma unroll
  for (int i = 0; i < 8; i++){
    float v = bestv[i]; int ix = besti[i];
    #pragma unroll
    for (int off = 8; off > 0; off >>= 1){
      float ov = __shfl_down(v, off, 16);
      int   oi = __shfl_down(ix, off, 16);
      if (ov < v || (ov == v && oi < ix)){ v = ov; ix = oi; }
    }
    if (tx == 0) idsf[ty*8 + i] = ix;
  }
  __syncthreads();
  if (tid < 128) out[(size_t)2*Nn*Dd + (size_t)blk*128 + tid] = (float)idsf[tid];
  const int m = tid & 127, cg = tid >> 7;
  const int myidx = idsf[m];
  const float* crow = cb + (size_t)myidx * Dd + cg*128;
  float* q  = out + (size_t)b * Dd * SPB + (size_t)cg * 128 * SPB + sb + m;
  float* st = q + (size_t)Nn * Dd;
  #pragma unroll 8
  for (int r = 0; r < 128; r++){
    const float v = crow[r];
    q[(size_t)r * SPB]  = v;
    st[(size_t)r * SPB] = v;
  }
}

// ---------- launcher ----------
extern "C" void kernel_launch(void* const* d_in, const int* in_sizes, int n_in,
                              void* d_out, int out_size, void* d_ws, size_t ws_size,
                              hipStream_t stream){
  const float* z  = (const float*)d_in[0];
  const float* cb = (const float*)d_in[1];
  float* out = (float*)d_out;

  const size_t BG_B  = (size_t)4 * 8 * 1024 * 16;     // 512 KiB
  const size_t CN_B  = (size_t)Kk * 4;                // 4 KiB
  const size_t CNT_B = (size_t)Nn * 4;                // 512 KiB
  const size_t CAN_B = (size_t)Nn * CCAP * 2;         // 4 MiB
  const size_t ABW_B = (size_t)Nn * 4;                // 512 KiB
  const size_t IDS_B = (size_t)Nn * 4;                // 512 KiB
  const size_t HC_B  = 256;                           // heavy counter (padded)
  const size_t HL_B  = (size_t)Nn * 4;                // 512 KiB
  const size_t NEED = BG_B + CN_B + CNT_B + CAN_B + ABW_B + IDS_B + HC_B + HL_B;

  if (ws_size >= NEED){
    uint8_t* ws = (uint8_t*)d_ws;
    size_t o = 0;
    uint4* Bg   = (uint4*)(ws + o);          o += BG_B;
    float* cnG  = (float*)(ws + o);          o += CN_B;
    int*   cntW = (int*)(ws + o);            o += CNT_B;
    unsigned short* candW = (unsigned short*)(ws + o); o += CAN_B;
    int*   abW  = (int*)(ws + o);            o += ABW_B;
    int*   idsW = (int*)(ws + o);            o += IDS_B;
    int*   hCnt = (int*)(ws + o);            o += HC_B;
    int*   hLst = (int*)(ws + o);            o += HL_B;

    cnorm_k<<<Kk, 64, 0, stream>>>(cb, cnG, hCnt);
    cconv_k<<<4, 256, 0, stream>>>(cb, Bg);
    vq_sweep_k<<<Nn/128, 512, 0, stream>>>(z, Bg, cnG, cntW, candW, abW,
                                           hCnt, hLst, idsW, out);
    vq_rescore_k<<<Nn/256, 256, 0, stream>>>(z, cb, cnG, cntW, candW, abW,
                                             hCnt, hLst, idsW, out);
    vq_gather_k<<<Nn/64, 256, 0, stream>>>(cb, idsW, out);
  } else {
    float* cn = (float*)d_ws;
    cnorm_k<<<Kk, 64, 0, stream>>>(cb, cn, (int*)(cn + Kk));
    vq_k<<<Nn/128, 256, 0, stream>>>(z, cb, cn, out);
  }
}

// Round 4
// 606.714 us; speedup vs baseline: 1.2965x; 1.1327x over previous
//
#include <hip/hip_runtime.h>
#include <stdint.h>

// VQ-VAE codebook quantize: z (8,256,16,32,32) f32, codebook (1024,256) f32.
// Outputs (concat in d_out, f32): quantized, st (== quantized fwd), indices.
// R8: rescore rebuilt as region-cooperative kernel.
//  - sweep (R7-proven) now emits PER-REGION heavy lists (no global atomic).
//  - rescore: 1 block / 128-token region; z staged to LDS in 4 coalesced
//    32KB chunks (fixes R7's 272MB scattered FETCH -> ~135MB coalesced);
//    per-candidate fmaf chains carried across chunks, d ascending ->
//    bit-identical arithmetic to R7's rescore (incl. overflow abest path).

constexpr int Dd  = 256;
constexpr int SPB = 16384;          // 16*32*32
constexpr int Nn  = 131072;         // 8*SPB tokens
constexpr int Kk  = 1024;
constexpr int CCAP = 16;            // candidate cap per token (avg ~1.2, P(>16)~0)
#define WWIN 2.2e-3f                // collect window; >= 2x approx err + quant

typedef short short8 __attribute__((ext_vector_type(8)));
typedef float v4f    __attribute__((ext_vector_type(4)));

__device__ __forceinline__ unsigned bf16pk(float a, float b){  // RNE pack 2xbf16
  unsigned ua = __float_as_uint(a), ub = __float_as_uint(b);
  ua = (ua + 0x7fffu + ((ua >> 16) & 1u)) >> 16;
  ub = (ub + 0x7fffu + ((ub >> 16) & 1u)) & 0xffff0000u;
  return ua | ub;
}
__device__ __forceinline__ short8 frg(uint4 u){
  union { uint4 a; short8 b; } x; x.a = u; return x.b;
}
__device__ __forceinline__ v4f mfma16(short8 a, short8 b, v4f c){
  return __builtin_amdgcn_mfma_f32_16x16x32_bf16(a, b, c, 0, 0, 0);
}
__device__ __forceinline__ void dma16(const void* g, void* l){
  __builtin_amdgcn_global_load_lds((const __attribute__((address_space(1))) void*)g,
                                   (__attribute__((address_space(3))) void*)l, 16, 0, 0);
}

// ---------- prepass: ||e_k||^2 ----------
__global__ __launch_bounds__(64) void cnorm_k(const float* __restrict__ cb,
                                              float* __restrict__ cn){
  const int k = blockIdx.x, l = threadIdx.x;
  const float* row = cb + (size_t)k * Dd;
  float s = 0.f;
  #pragma unroll
  for (int c = 0; c < Dd; c += 64){ float v = row[c + l]; s += v * v; }
  #pragma unroll
  for (int off = 32; off > 0; off >>= 1) s += __shfl_down(s, off, 64);
  if (l == 0) cn[k] = s;
}

// ---------- prepass: codebook -> bf16 hi fragment plane ----------
// Bg: [cc 0..3][dc 0..7][kq 0..3][n 0..255] x 16B
__global__ __launch_bounds__(256) void cconv_k(const float* __restrict__ cb,
                                               uint4* __restrict__ Bg){
  const int cc = blockIdx.x, n = threadIdx.x;
  const float* row = cb + (size_t)(cc * 256 + n) * Dd;
  for (int dc = 0; dc < 8; dc++){
    float v[32];
    const float4* rp = (const float4*)(row + dc * 32);
    #pragma unroll
    for (int q = 0; q < 8; q++){
      float4 f = rp[q]; v[4*q]=f.x; v[4*q+1]=f.y; v[4*q+2]=f.z; v[4*q+3]=f.w;
    }
    unsigned hv[16];
    #pragma unroll
    for (int p = 0; p < 16; p++) hv[p] = bf16pk(v[2*p], v[2*p+1]);
    size_t base = ((size_t)cc * 8 + dc) * 1024;
    #pragma unroll
    for (int kq = 0; kq < 4; kq++)
      Bg[base + (size_t)kq*256 + n] = make_uint4(hv[4*kq],hv[4*kq+1],hv[4*kq+2],hv[4*kq+3]);
  }
}

// ---------- phase 1: A-in-register MFMA sweep (16 tokens/wave, spill-free) ----
// 512 threads = 8 waves; wave w owns tokens [bId*128 + w*16, +16).
// Light tokens (cnt==1) finalized here; heavy tokens -> per-region list.
__global__ __launch_bounds__(512, 4) void vq_sweep_k(const float* __restrict__ z,
                                                     const uint4* __restrict__ Bg,
                                                     const float* __restrict__ cnG,
                                                     int* __restrict__ cntW,
                                                     unsigned short* __restrict__ candW,
                                                     int* __restrict__ abestW,
                                                     int* __restrict__ hCntB,
                                                     int* __restrict__ heavyRegion,
                                                     int* __restrict__ idsW,
                                                     float* __restrict__ out){
  __shared__ uint4 Bs[2][2048];    // 64 KiB: [buf][dc 0..7][kq 0..3][n 0..63]
  __shared__ float cnS[1024];      // 4 KiB
  __shared__ int hN;
  __shared__ int hT[128];

  const int tid = threadIdx.x, bId = blockIdx.x;
  const int w = tid >> 6, ln = tid & 63;
  const int li = ln & 15, lq = ln >> 4;

  if (tid == 0) hN = 0;

  // ---- stage cn (4 KiB) + B chunk 0 first (overlaps the A-load below) ----
  if (w < 4) dma16((const uint4*)cnG + w*64 + ln, (uint4*)&cnS[w*256]);
  int bOff[4];
  #pragma unroll
  for (int j = 0; j < 4; j++){
    const int f = j*512 + tid;              // [dc][kq][nl] flat
    bOff[j] = (f >> 8)*1024 + ((f >> 6) & 3)*256 + (f & 63);
  }
  #pragma unroll
  for (int j = 0; j < 4; j++)
    dma16(Bg + bOff[j], &Bs[0][j*512 + w*64]);

  // ---- A: z -> bf16 frags in registers (verified bf16pk chain) ----
  const int tok0 = bId * 128;
  const int b = tok0 >> 14;                 // uniform per block
  const int s0 = tok0 & 16383;
  const float* zb = z + (size_t)b * Dd * SPB + s0;
  short8 aF[8];
  const int tl = w*16 + li;                 // token within block (A-frag row)
  #pragma unroll
  for (int kk = 0; kk < 8; kk++){
    float v[8];
    #pragma unroll
    for (int j = 0; j < 8; j++)
      v[j] = zb[(size_t)(kk*32 + lq*8 + j) * SPB + tl];
    union { unsigned u[4]; short8 s8; } x;
    #pragma unroll
    for (int p = 0; p < 4; p++) x.u[p] = bf16pk(v[2*p], v[2*p+1]);
    aF[kk] = x.s8;
  }

  unsigned bestR[4], thrU[4]; int cntR[4];
  #pragma unroll
  for (int i = 0; i < 4; i++){ bestR[i] = 0xFFFFFFFFu; thrU[i] = 0u; cntR[i] = 0; }

  for (int c = 0; c < 16; c++){
    // stage chunk c+1 into the other buffer
    if (c < 15){
      const int cn1 = c + 1;
      const int srcB = (cn1 >> 2)*8192 + (cn1 & 3)*64;
      uint4* dstB = &Bs[cn1 & 1][0];
      #pragma unroll
      for (int j = 0; j < 4; j++)
        dma16(Bg + srcB + bOff[j], dstB + j*512 + w*64);
      asm volatile("s_waitcnt vmcnt(4)" ::: "memory");   // chunk c loads done
    } else {
      asm volatile("s_waitcnt vmcnt(0)" ::: "memory");
    }
    __builtin_amdgcn_s_barrier();
    asm volatile("" ::: "memory");

    v4f acc[4];
    const v4f vz = {0.f, 0.f, 0.f, 0.f};
    #pragma unroll
    for (int ni = 0; ni < 4; ni++) acc[ni] = vz;

    const uint4* Bbase = &Bs[c & 1][lq*64 + li];
    __builtin_amdgcn_s_setprio(1);
    #pragma unroll
    for (int kk = 0; kk < 8; kk++){           // dc ascending: same K-order
      short8 b0 = frg(Bbase[kk*256 +  0]);
      short8 b1 = frg(Bbase[kk*256 + 16]);
      short8 b2 = frg(Bbase[kk*256 + 32]);
      short8 b3 = frg(Bbase[kk*256 + 48]);
      acc[0] = mfma16(aF[kk], b0, acc[0]);
      acc[1] = mfma16(aF[kk], b1, acc[1]);
      acc[2] = mfma16(aF[kk], b2, acc[2]);
      acc[3] = mfma16(aF[kk], b3, acc[3]);
    }
    __builtin_amdgcn_s_setprio(0);

    float cnv[4];
    #pragma unroll
    for (int ni = 0; ni < 4; ni++) cnv[ni] = cnS[c*64 + ni*16 + li];

    // ---- wave-local epilogue: pack, reduce over li, collect ----
    const int codeB = c*64 + li;
    #pragma unroll
    for (int r = 0; r < 4; r++){
      unsigned pv[4];
      unsigned pm = 0xFFFFFFFFu;
      #pragma unroll
      for (int ni = 0; ni < 4; ni++){
        float s = fmaf(acc[ni][r], -2.0f, cnv[ni]);          // zn cancels
        unsigned u = __float_as_uint(s);
        u ^= (unsigned)((int)u >> 31) | 0x80000000u;          // sortable uint
        unsigned p = (u & 0xFFFFFC00u) | (unsigned)(codeB + ni*16);
        pv[ni] = p;
        pm = (pm < p) ? pm : p;
      }
      unsigned pmw = pm;
      #pragma unroll
      for (int off = 1; off < 16; off <<= 1){
        unsigned o = (unsigned)__shfl_xor((int)pmw, off, 16);
        pmw = (pmw < o) ? pmw : o;
      }
      if (pmw <= bestR[r]){                   // always true at c==0
        bestR[r] = pmw;
        unsigned bp = pmw & 0xFFFFFC00u;
        unsigned fb = (bp & 0x80000000u) ? (bp ^ 0x80000000u) : ~bp;
        float thrf = __uint_as_float(fb) + WWIN;
        unsigned tu = __float_as_uint(thrf);
        tu ^= (unsigned)((int)tu >> 31) | 0x80000000u;
        thrU[r] = tu | 1023u;                 // inclusive of code bits
      }
      if (__any(pm <= thrU[r])){              // fast-skip most chunks
        const int tok = tok0 + w*16 + lq*4 + r;
        int base = cntR[r];
        #pragma unroll
        for (int ni = 0; ni < 4; ni++){
          const unsigned p = pv[ni];
          const bool pass = (p <= thrU[r]);
          unsigned long long bal = __ballot(pass);
          const unsigned bq = (unsigned)(bal >> (lq*16)) & 0xFFFFu;
          if (pass){
            int pos = base + __popc(bq & ((1u << li) - 1u));
            if (pos < CCAP)
              candW[(size_t)tok*CCAP + pos] = (unsigned short)(p & 1023u);
          }
          base += __popc(bq);
        }
        cntR[r] = base;
      }
    }
    __builtin_amdgcn_s_barrier();      // reads of buf[c&1] done -> reusable
    asm volatile("" ::: "memory");
  }

  // ---- final dump: light tokens finalized, heavy tokens -> region list ----
  if (li == 0){
    #pragma unroll
    for (int r = 0; r < 4; r++){
      const int tok = tok0 + w*16 + lq*4 + r;
      if (cntR[r] == 1){
        const int code = (int)(bestR[r] & 1023u);
        idsW[tok] = code;
        out[(size_t)2 * Nn * Dd + tok] = (float)code;
      } else {
        int p = atomicAdd(&hN, 1);
        hT[p] = tok;
        cntW[tok] = cntR[r];
        abestW[tok] = (int)(bestR[r] & 1023u);
      }
    }
  }
  __syncthreads();
  if (tid == 0) hCntB[bId] = hN;
  if (tid < hN) heavyRegion[bId*128 + tid] = hT[tid];
}

// ---------- phase 2: region-cooperative exact fp32 rescore ----------
// 1 block / 128-token region; z staged in 4 coalesced 32KB LDS chunks.
// fmaf chains carried across chunks, d ascending -> bit-identical to R7.
__global__ __launch_bounds__(256) void vq_rescore_k(const float* __restrict__ z,
                                                    const float* __restrict__ cb,
                                                    const float* __restrict__ cnG,
                                                    const int* __restrict__ cntW,
                                                    const unsigned short* __restrict__ candW,
                                                    const int* __restrict__ abestW,
                                                    const int* __restrict__ hCntB,
                                                    const int* __restrict__ heavyRegion,
                                                    int* __restrict__ idsW,
                                                    float* __restrict__ out){
  __shared__ float zS[64][128];               // 32 KiB chunk tile
  const int tid = threadIdx.x, reg = blockIdx.x;   // 1024 regions
  const int h = hCntB[reg];
  if (h == 0) return;                         // uniform per block

  const int tok0 = reg * 128;
  const int b = tok0 >> 14, sb = tok0 & 16383;
  const float* zb = z + (size_t)b * Dd * SPB + sb;

  const bool act = tid < h;
  int tok = 0, tl = 0, n = 0, abest = 0;
  bool ovf = false;
  unsigned short cds[CCAP];
  if (act){
    tok = heavyRegion[reg*128 + tid];
    tl = tok & 127;
    n = cntW[tok];
    ovf = (n > CCAP);
    if (ovf) n = CCAP;
    *(uint4*)&cds[0] = *(const uint4*)&candW[(size_t)tok * CCAP];
    *(uint4*)&cds[8] = *(const uint4*)&candW[(size_t)tok * CCAP + 8];
    abest = abestW[tok];
  }
  const int eIdx = act ? (ovf ? abest : (int)cds[0]) : 0;   // extra (ovf) slot

  float accs[CCAP];
  #pragma unroll
  for (int i = 0; i < CCAP; i++) accs[i] = 0.f;
  float accE = 0.f, za = 0.f;

  for (int ch = 0; ch < 4; ch++){
    if (ch) __syncthreads();                  // protect prior chunk reads
    // stage dims [ch*64, +64): 2048 float4, 8 per thread, coalesced rows
    #pragma unroll
    for (int rr = 0; rr < 8; rr++){
      const int f4 = rr*256 + tid;
      const int row = f4 >> 5, c4 = f4 & 31;
      const float4 v = *(const float4*)(zb + (size_t)(ch*64 + row) * SPB + c4*4);
      *(float4*)&zS[row][c4*4] = v;
    }
    __syncthreads();
    if (act){
      // ||z||^2 partial: single fmaf chain carried across chunks, d ascending
      #pragma unroll 8
      for (int d = 0; d < 64; d++){
        const float v = zS[d][tl];
        za = fmaf(v, v, za);
      }
      // candidate dots (static indexing; predicated per unrolled ci)
      #pragma unroll
      for (int ci = 0; ci < CCAP; ci++){
        if (ci < n){
          const float* cr = cb + (size_t)cds[ci] * Dd + ch*64;
          float a = accs[ci];
          #pragma unroll
          for (int d = 0; d < 64; d += 4){
            const float4 cv = *(const float4*)(cr + d);
            a = fmaf(zS[d+0][tl], cv.x, a);
            a = fmaf(zS[d+1][tl], cv.y, a);
            a = fmaf(zS[d+2][tl], cv.z, a);
            a = fmaf(zS[d+3][tl], cv.w, a);
          }
          accs[ci] = a;
        }
      }
      if (ovf){
        const float* cr = cb + (size_t)eIdx * Dd + ch*64;
        float a = accE;
        #pragma unroll
        for (int d = 0; d < 64; d += 4){
          const float4 cv = *(const float4*)(cr + d);
          a = fmaf(zS[d+0][tl], cv.x, a);
          a = fmaf(zS[d+1][tl], cv.y, a);
          a = fmaf(zS[d+2][tl], cv.z, a);
          a = fmaf(zS[d+3][tl], cv.w, a);
        }
        accE = a;
      }
    }
  }

  if (act){
    float bv = 3.4e38f; int bi = 0x7fffffff;
    #pragma unroll
    for (int ci = 0; ci < CCAP; ci++){
      if (ci < n){
        const int ix = (int)cds[ci];
        float t  = za - 2.0f * accs[ci];
        float d2 = t + cnG[ix];
        if (d2 < bv || (d2 == bv && ix < bi)){ bv = d2; bi = ix; }
      }
    }
    if (ovf){
      float t  = za - 2.0f * accE;
      float d2 = t + cnG[eIdx];
      if (d2 < bv || (d2 == bv && eIdx < bi)){ bv = d2; bi = eIdx; }
    }
    idsW[tok] = bi;
    out[(size_t)2 * Nn * Dd + tok] = (float)bi;
  }
}

// ---------- phase 3: LDS-transpose gather ----------
__global__ __launch_bounds__(256) void vq_gather_k(const float* __restrict__ cb,
                                                   const int* __restrict__ idsW,
                                                   float* __restrict__ out){
  __shared__ float tile[64][129];
  __shared__ int lid[64];
  const int tid = threadIdx.x, blk = blockIdx.x;   // 2048 blocks
  const int b = blk >> 8, s0 = (blk & 255) * 64;
  if (tid < 64) lid[tid] = idsW[b * SPB + s0 + tid];
  __syncthreads();

  const int r2 = tid >> 7, c = tid & 127;          // load mapping
  const int s = tid & 63, cq = tid >> 6;           // store mapping
  float* qb  = out + (size_t)b * Dd * SPB + s0 + s;
  float* stb = qb + (size_t)Nn * Dd;

  for (int ch = 0; ch < 2; ch++){
    #pragma unroll 4
    for (int t0 = 0; t0 < 64; t0 += 2){
      const int row = t0 + r2;
      tile[row][c] = cb[(size_t)lid[row] * Dd + ch*128 + c];
    }
    __syncthreads();
    #pragma unroll 8
    for (int i = 0; i < 32; i++){
      const int cc2 = i*4 + cq;
      const float v = tile[s][cc2];
      const size_t off = (size_t)(ch*128 + cc2) * SPB;
      qb[off]  = v;
      stb[off] = v;
    }
    __syncthreads();
  }
}

// ================= R1 fp32 fallback (used if ws too small) =================
#define MICRO_STEP(WITH_ZN)                                                    \
    {                                                                          \
        float4 a0 = *(const float4*)&As[d][ty * 8];                            \
        float4 a1 = *(const float4*)&As[d][ty * 8 + 4];                        \
        float4 b0 = *(const float4*)&Bs[d][tx * 8];                            \
        float4 b1 = *(const float4*)&Bs[d][tx * 8 + 4];                        \
        float a[8] = {a0.x, a0.y, a0.z, a0.w, a1.x, a1.y, a1.z, a1.w};         \
        float bb[8] = {b0.x, b0.y, b0.z, b0.w, b1.x, b1.y, b1.z, b1.w};        \
        _Pragma("unroll")                                                      \
        for (int i = 0; i < 8; i++) {                                          \
            _Pragma("unroll")                                                  \
            for (int j = 0; j < 8; j++) acc[i][j] += a[i] * bb[j];             \
            if (WITH_ZN) zn[i] += a[i] * a[i];                                 \
        }                                                                      \
    }

__global__ __launch_bounds__(256) void vq_k(const float* __restrict__ z,
                                            const float* __restrict__ cb,
                                            const float* __restrict__ cn,
                                            float* __restrict__ out){
  __shared__ float As[16][128];
  __shared__ float Bs[16][132];
  __shared__ int   idsf[128];
  const int tid = threadIdx.x;
  const int tx = tid & 15, ty = tid >> 4;
  const int blk = blockIdx.x;
  const int b = blk >> 7, sb = (blk & 127) * 128;
  const float* zb = z + (size_t)b * Dd * SPB + sb;
  float bestv[8]; int besti[8]; float zn[8];
  #pragma unroll
  for (int i = 0; i < 8; i++){ bestv[i] = 3.4e38f; besti[i] = 0; zn[i] = 0.f; }
  const int am = tid & 127, ad = tid >> 7;
  const int bd = tid & 15,  bk = tid >> 4;
  for (int cc = 0; cc < 8; cc++){
    float acc[8][8];
    #pragma unroll
    for (int i = 0; i < 8; i++)
      #pragma unroll
      for (int j = 0; j < 8; j++) acc[i][j] = 0.f;
    for (int dc = 0; dc < 16; dc++){
      #pragma unroll
      for (int r = 0; r < 8; r++){
        const int d = ad + r * 2;
        As[d][am] = zb[(size_t)(dc*16 + d) * SPB + am];
      }
      #pragma unroll
      for (int r = 0; r < 8; r++){
        const int k = bk + r * 16;
        Bs[bd][k] = cb[(size_t)(cc*128 + k) * Dd + dc*16 + bd];
      }
      __syncthreads();
      if (cc == 0){
        #pragma unroll
        for (int d = 0; d < 16; d++) MICRO_STEP(1)
      } else {
        #pragma unroll
        for (int d = 0; d < 16; d++) MICRO_STEP(0)
      }
      __syncthreads();
    }
    const float* cnp = cn + cc*128 + tx*8;
    float4 c0 = *(const float4*)cnp;
    float4 c1 = *(const float4*)(cnp + 4);
    float cv[8] = {c0.x, c0.y, c0.z, c0.w, c1.x, c1.y, c1.z, c1.w};
    #pragma unroll
    for (int i = 0; i < 8; i++){
      #pragma unroll
      for (int j = 0; j < 8; j++){
        float t  = zn[i] - 2.0f * acc[i][j];
        float d2 = t + cv[j];
        int   ix = cc*128 + tx*8 + j;
        if (d2 < bestv[i]){ bestv[i] = d2; besti[i] = ix; }
      }
    }
  }
  #pragma unroll
  for (int i = 0; i < 8; i++){
    float v = bestv[i]; int ix = besti[i];
    #pragma unroll
    for (int off = 8; off > 0; off >>= 1){
      float ov = __shfl_down(v, off, 16);
      int   oi = __shfl_down(ix, off, 16);
      if (ov < v || (ov == v && oi < ix)){ v = ov; ix = oi; }
    }
    if (tx == 0) idsf[ty*8 + i] = ix;
  }
  __syncthreads();
  if (tid < 128) out[(size_t)2*Nn*Dd + (size_t)blk*128 + tid] = (float)idsf[tid];
  const int m = tid & 127, cg = tid >> 7;
  const int myidx = idsf[m];
  const float* crow = cb + (size_t)myidx * Dd + cg*128;
  float* q  = out + (size_t)b * Dd * SPB + (size_t)cg * 128 * SPB + sb + m;
  float* st = q + (size_t)Nn * Dd;
  #pragma unroll 8
  for (int r = 0; r < 128; r++){
    const float v = crow[r];
    q[(size_t)r * SPB]  = v;
    st[(size_t)r * SPB] = v;
  }
}

// ---------- launcher ----------
extern "C" void kernel_launch(void* const* d_in, const int* in_sizes, int n_in,
                              void* d_out, int out_size, void* d_ws, size_t ws_size,
                              hipStream_t stream){
  const float* z  = (const float*)d_in[0];
  const float* cb = (const float*)d_in[1];
  float* out = (float*)d_out;

  const size_t BG_B  = (size_t)4 * 8 * 1024 * 16;     // 512 KiB
  const size_t CN_B  = (size_t)Kk * 4;                // 4 KiB
  const size_t CNT_B = (size_t)Nn * 4;                // 512 KiB
  const size_t CAN_B = (size_t)Nn * CCAP * 2;         // 4 MiB
  const size_t ABW_B = (size_t)Nn * 4;                // 512 KiB
  const size_t IDS_B = (size_t)Nn * 4;                // 512 KiB
  const size_t HCB_B = (size_t)(Nn/128) * 4;          // 4 KiB
  const size_t HR_B  = (size_t)Nn * 4;                // 512 KiB
  const size_t NEED = BG_B + CN_B + CNT_B + CAN_B + ABW_B + IDS_B + HCB_B + HR_B;

  if (ws_size >= NEED){
    uint8_t* ws = (uint8_t*)d_ws;
    size_t o = 0;
    uint4* Bg   = (uint4*)(ws + o);          o += BG_B;
    float* cnG  = (float*)(ws + o);          o += CN_B;
    int*   cntW = (int*)(ws + o);            o += CNT_B;
    unsigned short* candW = (unsigned short*)(ws + o); o += CAN_B;
    int*   abW  = (int*)(ws + o);            o += ABW_B;
    int*   idsW = (int*)(ws + o);            o += IDS_B;
    int*   hCB  = (int*)(ws + o);            o += HCB_B;
    int*   hReg = (int*)(ws + o);            o += HR_B;

    cnorm_k<<<Kk, 64, 0, stream>>>(cb, cnG);
    cconv_k<<<4, 256, 0, stream>>>(cb, Bg);
    vq_sweep_k<<<Nn/128, 512, 0, stream>>>(z, Bg, cnG, cntW, candW, abW,
                                           hCB, hReg, idsW, out);
    vq_rescore_k<<<Nn/128, 256, 0, stream>>>(z, cb, cnG, cntW, candW, abW,
                                             hCB, hReg, idsW, out);
    vq_gather_k<<<Nn/64, 256, 0, stream>>>(cb, idsW, out);
  } else {
    float* cn = (float*)d_ws;
    cnorm_k<<<Kk, 64, 0, stream>>>(cb, cn);
    vq_k<<<Nn/128, 256, 0, stream>>>(z, cb, cn, out);
  }
}

// Round 5
// 597.793 us; speedup vs baseline: 1.3158x; 1.0149x over previous
//
#include <hip/hip_runtime.h>
#include <stdint.h>

// VQ-VAE codebook quantize: z (8,256,16,32,32) f32, codebook (1024,256) f32.
// Outputs (concat in d_out, f32): quantized, st (== quantized fwd), indices.
// R9:
//  - sweep: epilogue software-pipelined one chunk behind the MFMAs (accA/accB,
//    static indexing) so the pack/shfl/collect VALU overlaps the MFMA pipe.
//    Numerics and candidate order identical to R8.
//  - rescore + gather fused into vq_finish_k (1 block / 128-token region):
//    R8-proven exact rescore, heavy ids published to LDS, then the proven
//    LDS-transpose gather for both 64-token halves. One launch fewer, ids
//    round-trip removed, rescore compute overlaps the q/st write stream.

constexpr int Dd  = 256;
constexpr int SPB = 16384;          // 16*32*32
constexpr int Nn  = 131072;         // 8*SPB tokens
constexpr int Kk  = 1024;
constexpr int CCAP = 16;            // candidate cap per token (avg ~1.2, P(>16)~0)
#define WWIN 2.2e-3f                // collect window; >= 2x approx err + quant

typedef short short8 __attribute__((ext_vector_type(8)));
typedef float v4f    __attribute__((ext_vector_type(4)));

__device__ __forceinline__ unsigned bf16pk(float a, float b){  // RNE pack 2xbf16
  unsigned ua = __float_as_uint(a), ub = __float_as_uint(b);
  ua = (ua + 0x7fffu + ((ua >> 16) & 1u)) >> 16;
  ub = (ub + 0x7fffu + ((ub >> 16) & 1u)) & 0xffff0000u;
  return ua | ub;
}
__device__ __forceinline__ short8 frg(uint4 u){
  union { uint4 a; short8 b; } x; x.a = u; return x.b;
}
__device__ __forceinline__ v4f mfma16(short8 a, short8 b, v4f c){
  return __builtin_amdgcn_mfma_f32_16x16x32_bf16(a, b, c, 0, 0, 0);
}
__device__ __forceinline__ void dma16(const void* g, void* l){
  __builtin_amdgcn_global_load_lds((const __attribute__((address_space(1))) void*)g,
                                   (__attribute__((address_space(3))) void*)l, 16, 0, 0);
}

// ---------- prepass: ||e_k||^2 ----------
__global__ __launch_bounds__(64) void cnorm_k(const float* __restrict__ cb,
                                              float* __restrict__ cn){
  const int k = blockIdx.x, l = threadIdx.x;
  const float* row = cb + (size_t)k * Dd;
  float s = 0.f;
  #pragma unroll
  for (int c = 0; c < Dd; c += 64){ float v = row[c + l]; s += v * v; }
  #pragma unroll
  for (int off = 32; off > 0; off >>= 1) s += __shfl_down(s, off, 64);
  if (l == 0) cn[k] = s;
}

// ---------- prepass: codebook -> bf16 hi fragment plane ----------
// Bg: [cc 0..3][dc 0..7][kq 0..3][n 0..255] x 16B
__global__ __launch_bounds__(256) void cconv_k(const float* __restrict__ cb,
                                               uint4* __restrict__ Bg){
  const int cc = blockIdx.x, n = threadIdx.x;
  const float* row = cb + (size_t)(cc * 256 + n) * Dd;
  for (int dc = 0; dc < 8; dc++){
    float v[32];
    const float4* rp = (const float4*)(row + dc * 32);
    #pragma unroll
    for (int q = 0; q < 8; q++){
      float4 f = rp[q]; v[4*q]=f.x; v[4*q+1]=f.y; v[4*q+2]=f.z; v[4*q+3]=f.w;
    }
    unsigned hv[16];
    #pragma unroll
    for (int p = 0; p < 16; p++) hv[p] = bf16pk(v[2*p], v[2*p+1]);
    size_t base = ((size_t)cc * 8 + dc) * 1024;
    #pragma unroll
    for (int kq = 0; kq < 4; kq++)
      Bg[base + (size_t)kq*256 + n] = make_uint4(hv[4*kq],hv[4*kq+1],hv[4*kq+2],hv[4*kq+3]);
  }
}

// ---------- sweep epilogue: pack, wave-local argmin, window collect ----------
__device__ __forceinline__ void epi(const v4f (&acc)[4], const int c,
                                    const int li, const int lq, const int w,
                                    const int tok0, const float* cnS,
                                    unsigned (&bestR)[4], unsigned (&thrU)[4],
                                    int (&cntR)[4],
                                    unsigned short* __restrict__ candW){
  float cnv[4];
  #pragma unroll
  for (int ni = 0; ni < 4; ni++) cnv[ni] = cnS[c*64 + ni*16 + li];
  const int codeB = c*64 + li;
  #pragma unroll
  for (int r = 0; r < 4; r++){
    unsigned pv[4];
    unsigned pm = 0xFFFFFFFFu;
    #pragma unroll
    for (int ni = 0; ni < 4; ni++){
      float s = fmaf(acc[ni][r], -2.0f, cnv[ni]);            // zn cancels
      unsigned u = __float_as_uint(s);
      u ^= (unsigned)((int)u >> 31) | 0x80000000u;            // sortable uint
      unsigned p = (u & 0xFFFFFC00u) | (unsigned)(codeB + ni*16);
      pv[ni] = p;
      pm = (pm < p) ? pm : p;
    }
    unsigned pmw = pm;
    #pragma unroll
    for (int off = 1; off < 16; off <<= 1){
      unsigned o = (unsigned)__shfl_xor((int)pmw, off, 16);
      pmw = (pmw < o) ? pmw : o;
    }
    if (pmw <= bestR[r]){                   // always true at c==0
      bestR[r] = pmw;
      unsigned bp = pmw & 0xFFFFFC00u;
      unsigned fb = (bp & 0x80000000u) ? (bp ^ 0x80000000u) : ~bp;
      float thrf = __uint_as_float(fb) + WWIN;
      unsigned tu = __float_as_uint(thrf);
      tu ^= (unsigned)((int)tu >> 31) | 0x80000000u;
      thrU[r] = tu | 1023u;                 // inclusive of code bits
    }
    if (__any(pm <= thrU[r])){              // fast-skip most chunks
      const int tok = tok0 + w*16 + lq*4 + r;
      int base = cntR[r];
      #pragma unroll
      for (int ni = 0; ni < 4; ni++){
        const unsigned p = pv[ni];
        const bool pass = (p <= thrU[r]);
        unsigned long long bal = __ballot(pass);
        const unsigned bq = (unsigned)(bal >> (lq*16)) & 0xFFFFu;
        if (pass){
          int pos = base + __popc(bq & ((1u << li) - 1u));
          if (pos < CCAP)
            candW[(size_t)tok*CCAP + pos] = (unsigned short)(p & 1023u);
        }
        base += __popc(bq);
      }
      cntR[r] = base;
    }
  }
}

// ---------- phase 1: A-in-register MFMA sweep, pipelined epilogue ----------
// 512 threads = 8 waves; wave w owns tokens [bId*128 + w*16, +16).
// Chunk c's MFMAs issue, then chunk c-1's epilogue runs (accA/accB ping-pong)
// so VALU epilogue overlaps the MFMA pipe. Light tokens finalized here;
// heavy tokens -> per-region list.
__global__ __launch_bounds__(512, 4) void vq_sweep_k(const float* __restrict__ z,
                                                     const uint4* __restrict__ Bg,
                                                     const float* __restrict__ cnG,
                                                     int* __restrict__ cntW,
                                                     unsigned short* __restrict__ candW,
                                                     int* __restrict__ abestW,
                                                     int* __restrict__ hCntB,
                                                     int* __restrict__ heavyRegion,
                                                     int* __restrict__ idsW,
                                                     float* __restrict__ out){
  __shared__ uint4 Bs[2][2048];    // 64 KiB: [buf][dc 0..7][kq 0..3][n 0..63]
  __shared__ float cnS[1024];      // 4 KiB
  __shared__ int hN;
  __shared__ int hT[128];

  const int tid = threadIdx.x, bId = blockIdx.x;
  const int w = tid >> 6, ln = tid & 63;
  const int li = ln & 15, lq = ln >> 4;

  if (tid == 0) hN = 0;

  // ---- stage cn (4 KiB) + B chunk 0 first (overlaps the A-load below) ----
  if (w < 4) dma16((const uint4*)cnG + w*64 + ln, (uint4*)&cnS[w*256]);
  int bOff[4];
  #pragma unroll
  for (int j = 0; j < 4; j++){
    const int f = j*512 + tid;              // [dc][kq][nl] flat
    bOff[j] = (f >> 8)*1024 + ((f >> 6) & 3)*256 + (f & 63);
  }
  #pragma unroll
  for (int j = 0; j < 4; j++)
    dma16(Bg + bOff[j], &Bs[0][j*512 + w*64]);

  // ---- A: z -> bf16 frags in registers (verified bf16pk chain) ----
  const int tok0 = bId * 128;
  const int b = tok0 >> 14;                 // uniform per block
  const int s0 = tok0 & 16383;
  const float* zb = z + (size_t)b * Dd * SPB + s0;
  short8 aF[8];
  const int tl = w*16 + li;                 // token within block (A-frag row)
  #pragma unroll
  for (int kk = 0; kk < 8; kk++){
    float v[8];
    #pragma unroll
    for (int j = 0; j < 8; j++)
      v[j] = zb[(size_t)(kk*32 + lq*8 + j) * SPB + tl];
    union { unsigned u[4]; short8 s8; } x;
    #pragma unroll
    for (int p = 0; p < 4; p++) x.u[p] = bf16pk(v[2*p], v[2*p+1]);
    aF[kk] = x.s8;
  }

  unsigned bestR[4], thrU[4]; int cntR[4];
  #pragma unroll
  for (int i = 0; i < 4; i++){ bestR[i] = 0xFFFFFFFFu; thrU[i] = 0u; cntR[i] = 0; }

  v4f accA[4], accB[4];
  const v4f vz = {0.f, 0.f, 0.f, 0.f};

  for (int cp = 0; cp < 8; cp++){
    const int c0 = cp*2, c1 = c0 + 1;

    // ===== chunk c0 (buf 0) =====
    {
      const int cn1 = c0 + 1;                       // <=15 always
      const int srcB = (cn1 >> 2)*8192 + (cn1 & 3)*64;
      #pragma unroll
      for (int j = 0; j < 4; j++)
        dma16(Bg + srcB + bOff[j], &Bs[1][j*512 + w*64]);
      asm volatile("s_waitcnt vmcnt(4)" ::: "memory");   // chunk c0 loads done
      __builtin_amdgcn_s_barrier();
      asm volatile("" ::: "memory");

      #pragma unroll
      for (int ni = 0; ni < 4; ni++) accA[ni] = vz;
      const uint4* Bbase = &Bs[0][lq*64 + li];
      __builtin_amdgcn_s_setprio(1);
      #pragma unroll
      for (int kk = 0; kk < 8; kk++){               // dc ascending: same K-order
        short8 b0 = frg(Bbase[kk*256 +  0]);
        short8 b1 = frg(Bbase[kk*256 + 16]);
        short8 b2 = frg(Bbase[kk*256 + 32]);
        short8 b3 = frg(Bbase[kk*256 + 48]);
        accA[0] = mfma16(aF[kk], b0, accA[0]);
        accA[1] = mfma16(aF[kk], b1, accA[1]);
        accA[2] = mfma16(aF[kk], b2, accA[2]);
        accA[3] = mfma16(aF[kk], b3, accA[3]);
      }
      __builtin_amdgcn_s_setprio(0);
      if (cp)                                        // epilogue for chunk c0-1
        epi(accB, c0 - 1, li, lq, w, tok0, cnS, bestR, thrU, cntR, candW);
      __builtin_amdgcn_s_barrier();                  // buf0 reads done
      asm volatile("" ::: "memory");
    }

    // ===== chunk c1 (buf 1) =====
    {
      if (c1 < 15){
        const int cn1 = c1 + 1;                      // even -> buf 0
        const int srcB = (cn1 >> 2)*8192 + (cn1 & 3)*64;
        #pragma unroll
        for (int j = 0; j < 4; j++)
          dma16(Bg + srcB + bOff[j], &Bs[0][j*512 + w*64]);
        asm volatile("s_waitcnt vmcnt(4)" ::: "memory"); // chunk c1 loads done
      } else {
        asm volatile("s_waitcnt vmcnt(0)" ::: "memory");
      }
      __builtin_amdgcn_s_barrier();
      asm volatile("" ::: "memory");

      #pragma unroll
      for (int ni = 0; ni < 4; ni++) accB[ni] = vz;
      const uint4* Bbase = &Bs[1][lq*64 + li];
      __builtin_amdgcn_s_setprio(1);
      #pragma unroll
      for (int kk = 0; kk < 8; kk++){
        short8 b0 = frg(Bbase[kk*256 +  0]);
        short8 b1 = frg(Bbase[kk*256 + 16]);
        short8 b2 = frg(Bbase[kk*256 + 32]);
        short8 b3 = frg(Bbase[kk*256 + 48]);
        accB[0] = mfma16(aF[kk], b0, accB[0]);
        accB[1] = mfma16(aF[kk], b1, accB[1]);
        accB[2] = mfma16(aF[kk], b2, accB[2]);
        accB[3] = mfma16(aF[kk], b3, accB[3]);
      }
      __builtin_amdgcn_s_setprio(0);
      epi(accA, c0, li, lq, w, tok0, cnS, bestR, thrU, cntR, candW);
      __builtin_amdgcn_s_barrier();                  // buf1 reads done
      asm volatile("" ::: "memory");
    }
  }
  epi(accB, 15, li, lq, w, tok0, cnS, bestR, thrU, cntR, candW);

  // ---- final dump: light tokens finalized, heavy tokens -> region list ----
  if (li == 0){
    #pragma unroll
    for (int r = 0; r < 4; r++){
      const int tok = tok0 + w*16 + lq*4 + r;
      if (cntR[r] == 1){
        const int code = (int)(bestR[r] & 1023u);
        idsW[tok] = code;
        out[(size_t)2 * Nn * Dd + tok] = (float)code;
      } else {
        int p = atomicAdd(&hN, 1);
        hT[p] = tok;
        cntW[tok] = cntR[r];
        abestW[tok] = (int)(bestR[r] & 1023u);
      }
    }
  }
  __syncthreads();
  if (tid == 0) hCntB[bId] = hN;
  if (tid < hN) heavyRegion[bId*128 + tid] = hT[tid];
}

// ---------- phase 2: fused exact rescore + LDS-transpose gather ----------
// 1 block / 128-token region. Rescore (R8-proven, bit-identical) for heavy
// tokens with z staged in 4 coalesced 32KB LDS chunks; heavy ids published to
// LDS; then the proven 64-token transpose gather runs for both halves.
__global__ __launch_bounds__(256) void vq_finish_k(const float* __restrict__ z,
                                                   const float* __restrict__ cb,
                                                   const float* __restrict__ cnG,
                                                   const int* __restrict__ cntW,
                                                   const unsigned short* __restrict__ candW,
                                                   const int* __restrict__ abestW,
                                                   const int* __restrict__ hCntB,
                                                   const int* __restrict__ heavyRegion,
                                                   const int* __restrict__ idsW,
                                                   float* __restrict__ out){
  __shared__ __align__(16) float smem[64*129];   // 33 KB: zS[64][128] / tile[64][129]
  __shared__ int idS[128];

  const int tid = threadIdx.x, reg = blockIdx.x;   // 1024 regions
  const int tok0 = reg * 128;
  const int b = tok0 >> 14, sb = tok0 & 16383;

  if (tid < 128) idS[tid] = idsW[tok0 + tid];      // heavy slots overwritten below

  const int h = hCntB[reg];
  if (h > 0){                                      // uniform per block
    float* zS = smem;                              // [64][128]
    const float* zb = z + (size_t)b * Dd * SPB + sb;

    const bool act = tid < h;
    int tok = 0, tl = 0, n = 0, abest = 0;
    bool ovf = false;
    unsigned short cds[CCAP];
    if (act){
      tok = heavyRegion[reg*128 + tid];
      tl = tok & 127;
      n = cntW[tok];
      ovf = (n > CCAP);
      if (ovf) n = CCAP;
      *(uint4*)&cds[0] = *(const uint4*)&candW[(size_t)tok * CCAP];
      *(uint4*)&cds[8] = *(const uint4*)&candW[(size_t)tok * CCAP + 8];
      abest = abestW[tok];
    }
    const int eIdx = act ? (ovf ? abest : (int)cds[0]) : 0;   // extra (ovf) slot

    float accs[CCAP];
    #pragma unroll
    for (int i = 0; i < CCAP; i++) accs[i] = 0.f;
    float accE = 0.f, za = 0.f;

    for (int ch = 0; ch < 4; ch++){
      if (ch) __syncthreads();                  // protect prior chunk reads
      #pragma unroll
      for (int rr = 0; rr < 8; rr++){
        const int f4 = rr*256 + tid;
        const int row = f4 >> 5, c4 = f4 & 31;
        const float4 v = *(const float4*)(zb + (size_t)(ch*64 + row) * SPB + c4*4);
        *(float4*)&zS[row*128 + c4*4] = v;
      }
      __syncthreads();
      if (act){
        #pragma unroll 8
        for (int d = 0; d < 64; d++){
          const float v = zS[d*128 + tl];
          za = fmaf(v, v, za);
        }
        #pragma unroll
        for (int ci = 0; ci < CCAP; ci++){
          if (ci < n){
            const float* cr = cb + (size_t)cds[ci] * Dd + ch*64;
            float a = accs[ci];
            #pragma unroll
            for (int d = 0; d < 64; d += 4){
              const float4 cv = *(const float4*)(cr + d);
              a = fmaf(zS[(d+0)*128 + tl], cv.x, a);
              a = fmaf(zS[(d+1)*128 + tl], cv.y, a);
              a = fmaf(zS[(d+2)*128 + tl], cv.z, a);
              a = fmaf(zS[(d+3)*128 + tl], cv.w, a);
            }
            accs[ci] = a;
          }
        }
        if (ovf){
          const float* cr = cb + (size_t)eIdx * Dd + ch*64;
          float a = accE;
          #pragma unroll
          for (int d = 0; d < 64; d += 4){
            const float4 cv = *(const float4*)(cr + d);
            a = fmaf(zS[(d+0)*128 + tl], cv.x, a);
            a = fmaf(zS[(d+1)*128 + tl], cv.y, a);
            a = fmaf(zS[(d+2)*128 + tl], cv.z, a);
            a = fmaf(zS[(d+3)*128 + tl], cv.w, a);
          }
          accE = a;
        }
      }
    }

    if (act){
      float bv = 3.4e38f; int bi = 0x7fffffff;
      #pragma unroll
      for (int ci = 0; ci < CCAP; ci++){
        if (ci < n){
          const int ix = (int)cds[ci];
          float t  = za - 2.0f * accs[ci];
          float d2 = t + cnG[ix];
          if (d2 < bv || (d2 == bv && ix < bi)){ bv = d2; bi = ix; }
        }
      }
      if (ovf){
        float t  = za - 2.0f * accE;
        float d2 = t + cnG[eIdx];
        if (d2 < bv || (d2 == bv && eIdx < bi)){ bv = d2; bi = eIdx; }
      }
      idS[tl] = bi;
      out[(size_t)2 * Nn * Dd + tok] = (float)bi;
    }
  }
  __syncthreads();                                 // idS final, smem free

  // ---- gather (proven mapping), two 64-token halves ----
  float* tile = smem;                              // [64][129]
  const int r2 = tid >> 7, ccol = tid & 127;       // load mapping
  const int s = tid & 63, cq = tid >> 6;           // store mapping
  for (int hh = 0; hh < 2; hh++){
    const int s0h = hh * 64;
    float* qb  = out + (size_t)b * Dd * SPB + sb + s0h + s;
    float* stb = qb + (size_t)Nn * Dd;
    for (int ch = 0; ch < 2; ch++){
      if (hh | ch) __syncthreads();                // protect prior tile reads
      #pragma unroll 4
      for (int t0 = 0; t0 < 64; t0 += 2){
        const int row = t0 + r2;
        tile[row*129 + ccol] = cb[(size_t)idS[s0h + row] * Dd + ch*128 + ccol];
      }
      __syncthreads();
      #pragma unroll 8
      for (int i = 0; i < 32; i++){
        const int cc2 = i*4 + cq;
        const float v = tile[s*129 + cc2];
        const size_t off = (size_t)(ch*128 + cc2) * SPB;
        qb[off]  = v;
        stb[off] = v;
      }
    }
  }
}

// ================= R1 fp32 fallback (used if ws too small) =================
#define MICRO_STEP(WITH_ZN)                                                    \
    {                                                                          \
        float4 a0 = *(const float4*)&As[d][ty * 8];                            \
        float4 a1 = *(const float4*)&As[d][ty * 8 + 4];                        \
        float4 b0 = *(const float4*)&Bs[d][tx * 8];                            \
        float4 b1 = *(const float4*)&Bs[d][tx * 8 + 4];                        \
        float a[8] = {a0.x, a0.y, a0.z, a0.w, a1.x, a1.y, a1.z, a1.w};         \
        float bb[8] = {b0.x, b0.y, b0.z, b0.w, b1.x, b1.y, b1.z, b1.w};        \
        _Pragma("unroll")                                                      \
        for (int i = 0; i < 8; i++) {                                          \
            _Pragma("unroll")                                                  \
            for (int j = 0; j < 8; j++) acc[i][j] += a[i] * bb[j];             \
            if (WITH_ZN) zn[i] += a[i] * a[i];                                 \
        }                                                                      \
    }

__global__ __launch_bounds__(256) void vq_k(const float* __restrict__ z,
                                            const float* __restrict__ cb,
                                            const float* __restrict__ cn,
                                            float* __restrict__ out){
  __shared__ float As[16][128];
  __shared__ float Bs[16][132];
  __shared__ int   idsf[128];
  const int tid = threadIdx.x;
  const int tx = tid & 15, ty = tid >> 4;
  const int blk = blockIdx.x;
  const int b = blk >> 7, sb = (blk & 127) * 128;
  const float* zb = z + (size_t)b * Dd * SPB + sb;
  float bestv[8]; int besti[8]; float zn[8];
  #pragma unroll
  for (int i = 0; i < 8; i++){ bestv[i] = 3.4e38f; besti[i] = 0; zn[i] = 0.f; }
  const int am = tid & 127, ad = tid >> 7;
  const int bd = tid & 15,  bk = tid >> 4;
  for (int cc = 0; cc < 8; cc++){
    float acc[8][8];
    #pragma unroll
    for (int i = 0; i < 8; i++)
      #pragma unroll
      for (int j = 0; j < 8; j++) acc[i][j] = 0.f;
    for (int dc = 0; dc < 16; dc++){
      #pragma unroll
      for (int r = 0; r < 8; r++){
        const int d = ad + r * 2;
        As[d][am] = zb[(size_t)(dc*16 + d) * SPB + am];
      }
      #pragma unroll
      for (int r = 0; r < 8; r++){
        const int k = bk + r * 16;
        Bs[bd][k] = cb[(size_t)(cc*128 + k) * Dd + dc*16 + bd];
      }
      __syncthreads();
      if (cc == 0){
        #pragma unroll
        for (int d = 0; d < 16; d++) MICRO_STEP(1)
      } else {
        #pragma unroll
        for (int d = 0; d < 16; d++) MICRO_STEP(0)
      }
      __syncthreads();
    }
    const float* cnp = cn + cc*128 + tx*8;
    float4 c0 = *(const float4*)cnp;
    float4 c1 = *(const float4*)(cnp + 4);
    float cv[8] = {c0.x, c0.y, c0.z, c0.w, c1.x, c1.y, c1.z, c1.w};
    #pragma unroll
    for (int i = 0; i < 8; i++){
      #pragma unroll
      for (int j = 0; j < 8; j++){
        float t  = zn[i] - 2.0f * acc[i][j];
        float d2 = t + cv[j];
        int   ix = cc*128 + tx*8 + j;
        if (d2 < bestv[i]){ bestv[i] = d2; besti[i] = ix; }
      }
    }
  }
  #pragma unroll
  for (int i = 0; i < 8; i++){
    float v = bestv[i]; int ix = besti[i];
    #pragma unroll
    for (int off = 8; off > 0; off >>= 1){
      float ov = __shfl_down(v, off, 16);
      int   oi = __shfl_down(ix, off, 16);
      if (ov < v || (ov == v && oi < ix)){ v = ov; ix = oi; }
    }
    if (tx == 0) idsf[ty*8 + i] = ix;
  }
  __syncthreads();
  if (tid < 128) out[(size_t)2*Nn*Dd + (size_t)blk*128 + tid] = (float)idsf[tid];
  const int m = tid & 127, cg = tid >> 7;
  const int myidx = idsf[m];
  const float* crow = cb + (size_t)myidx * Dd + cg*128;
  float* q  = out + (size_t)b * Dd * SPB + (size_t)cg * 128 * SPB + sb + m;
  float* st = q + (size_t)Nn * Dd;
  #pragma unroll 8
  for (int r = 0; r < 128; r++){
    const float v = crow[r];
    q[(size_t)r * SPB]  = v;
    st[(size_t)r * SPB] = v;
  }
}

// ---------- launcher ----------
extern "C" void kernel_launch(void* const* d_in, const int* in_sizes, int n_in,
                              void* d_out, int out_size, void* d_ws, size_t ws_size,
                              hipStream_t stream){
  const float* z  = (const float*)d_in[0];
  const float* cb = (const float*)d_in[1];
  float* out = (float*)d_out;

  const size_t BG_B  = (size_t)4 * 8 * 1024 * 16;     // 512 KiB
  const size_t CN_B  = (size_t)Kk * 4;                // 4 KiB
  const size_t CNT_B = (size_t)Nn * 4;                // 512 KiB
  const size_t CAN_B = (size_t)Nn * CCAP * 2;         // 4 MiB
  const size_t ABW_B = (size_t)Nn * 4;                // 512 KiB
  const size_t IDS_B = (size_t)Nn * 4;                // 512 KiB
  const size_t HCB_B = (size_t)(Nn/128) * 4;          // 4 KiB
  const size_t HR_B  = (size_t)Nn * 4;                // 512 KiB
  const size_t NEED = BG_B + CN_B + CNT_B + CAN_B + ABW_B + IDS_B + HCB_B + HR_B;

  if (ws_size >= NEED){
    uint8_t* ws = (uint8_t*)d_ws;
    size_t o = 0;
    uint4* Bg   = (uint4*)(ws + o);          o += BG_B;
    float* cnG  = (float*)(ws + o);          o += CN_B;
    int*   cntW = (int*)(ws + o);            o += CNT_B;
    unsigned short* candW = (unsigned short*)(ws + o); o += CAN_B;
    int*   abW  = (int*)(ws + o);            o += ABW_B;
    int*   idsW = (int*)(ws + o);            o += IDS_B;
    int*   hCB  = (int*)(ws + o);            o += HCB_B;
    int*   hReg = (int*)(ws + o);            o += HR_B;

    cnorm_k<<<Kk, 64, 0, stream>>>(cb, cnG);
    cconv_k<<<4, 256, 0, stream>>>(cb, Bg);
    vq_sweep_k<<<Nn/128, 512, 0, stream>>>(z, Bg, cnG, cntW, candW, abW,
                                           hCB, hReg, idsW, out);
    vq_finish_k<<<Nn/128, 256, 0, stream>>>(z, cb, cnG, cntW, candW, abW,
                                            hCB, hReg, idsW, out);
  } else {
    float* cn = (float*)d_ws;
    cnorm_k<<<Kk, 64, 0, stream>>>(cb, cn);
    vq_k<<<Nn/128, 256, 0, stream>>>(z, cb, cn, out);
  }
}

// Round 6
// 593.600 us; speedup vs baseline: 1.3251x; 1.0071x over previous
//
#include <hip/hip_runtime.h>
#include <stdint.h>

// VQ-VAE codebook quantize: z (8,256,16,32,32) f32, codebook (1024,256) f32.
// Outputs (concat in d_out, f32): quantized, st (== quantized fwd), indices.
// R10:
//  - sweep: R9-proven pipelined-epilogue MFMA sweep; dump now writes cntW for
//    ALL tokens (light=1) and drops the heavy-list compaction (no LDS atomics).
//  - finish: identity heavy mapping (thread tid owns token tid; active iff
//    cnt>1) -> rescore LDS reads are bank-conflict-free (R9's 1.4e7 conflicts
//    came from random compaction-order tl). Gather store phase rebuilt as
//    float4-across-tokens (4 stride-129 LDS reads + 1 dwordx4 store; 256B
//    coalesced segments). Rescore arithmetic bit-identical to R9.

constexpr int Dd  = 256;
constexpr int SPB = 16384;          // 16*32*32
constexpr int Nn  = 131072;         // 8*SPB tokens
constexpr int Kk  = 1024;
constexpr int CCAP = 16;            // candidate cap per token (avg ~1.2, P(>16)~0)
#define WWIN 2.2e-3f                // collect window; >= 2x approx err + quant

typedef short short8 __attribute__((ext_vector_type(8)));
typedef float v4f    __attribute__((ext_vector_type(4)));

__device__ __forceinline__ unsigned bf16pk(float a, float b){  // RNE pack 2xbf16
  unsigned ua = __float_as_uint(a), ub = __float_as_uint(b);
  ua = (ua + 0x7fffu + ((ua >> 16) & 1u)) >> 16;
  ub = (ub + 0x7fffu + ((ub >> 16) & 1u)) & 0xffff0000u;
  return ua | ub;
}
__device__ __forceinline__ short8 frg(uint4 u){
  union { uint4 a; short8 b; } x; x.a = u; return x.b;
}
__device__ __forceinline__ v4f mfma16(short8 a, short8 b, v4f c){
  return __builtin_amdgcn_mfma_f32_16x16x32_bf16(a, b, c, 0, 0, 0);
}
__device__ __forceinline__ void dma16(const void* g, void* l){
  __builtin_amdgcn_global_load_lds((const __attribute__((address_space(1))) void*)g,
                                   (__attribute__((address_space(3))) void*)l, 16, 0, 0);
}

// ---------- prepass: ||e_k||^2 ----------
__global__ __launch_bounds__(64) void cnorm_k(const float* __restrict__ cb,
                                              float* __restrict__ cn){
  const int k = blockIdx.x, l = threadIdx.x;
  const float* row = cb + (size_t)k * Dd;
  float s = 0.f;
  #pragma unroll
  for (int c = 0; c < Dd; c += 64){ float v = row[c + l]; s += v * v; }
  #pragma unroll
  for (int off = 32; off > 0; off >>= 1) s += __shfl_down(s, off, 64);
  if (l == 0) cn[k] = s;
}

// ---------- prepass: codebook -> bf16 hi fragment plane ----------
// Bg: [cc 0..3][dc 0..7][kq 0..3][n 0..255] x 16B
__global__ __launch_bounds__(256) void cconv_k(const float* __restrict__ cb,
                                               uint4* __restrict__ Bg){
  const int cc = blockIdx.x, n = threadIdx.x;
  const float* row = cb + (size_t)(cc * 256 + n) * Dd;
  for (int dc = 0; dc < 8; dc++){
    float v[32];
    const float4* rp = (const float4*)(row + dc * 32);
    #pragma unroll
    for (int q = 0; q < 8; q++){
      float4 f = rp[q]; v[4*q]=f.x; v[4*q+1]=f.y; v[4*q+2]=f.z; v[4*q+3]=f.w;
    }
    unsigned hv[16];
    #pragma unroll
    for (int p = 0; p < 16; p++) hv[p] = bf16pk(v[2*p], v[2*p+1]);
    size_t base = ((size_t)cc * 8 + dc) * 1024;
    #pragma unroll
    for (int kq = 0; kq < 4; kq++)
      Bg[base + (size_t)kq*256 + n] = make_uint4(hv[4*kq],hv[4*kq+1],hv[4*kq+2],hv[4*kq+3]);
  }
}

// ---------- sweep epilogue: pack, wave-local argmin, window collect ----------
__device__ __forceinline__ void epi(const v4f (&acc)[4], const int c,
                                    const int li, const int lq, const int w,
                                    const int tok0, const float* cnS,
                                    unsigned (&bestR)[4], unsigned (&thrU)[4],
                                    int (&cntR)[4],
                                    unsigned short* __restrict__ candW){
  float cnv[4];
  #pragma unroll
  for (int ni = 0; ni < 4; ni++) cnv[ni] = cnS[c*64 + ni*16 + li];
  const int codeB = c*64 + li;
  #pragma unroll
  for (int r = 0; r < 4; r++){
    unsigned pv[4];
    unsigned pm = 0xFFFFFFFFu;
    #pragma unroll
    for (int ni = 0; ni < 4; ni++){
      float s = fmaf(acc[ni][r], -2.0f, cnv[ni]);            // zn cancels
      unsigned u = __float_as_uint(s);
      u ^= (unsigned)((int)u >> 31) | 0x80000000u;            // sortable uint
      unsigned p = (u & 0xFFFFFC00u) | (unsigned)(codeB + ni*16);
      pv[ni] = p;
      pm = (pm < p) ? pm : p;
    }
    unsigned pmw = pm;
    #pragma unroll
    for (int off = 1; off < 16; off <<= 1){
      unsigned o = (unsigned)__shfl_xor((int)pmw, off, 16);
      pmw = (pmw < o) ? pmw : o;
    }
    if (pmw <= bestR[r]){                   // always true at c==0
      bestR[r] = pmw;
      unsigned bp = pmw & 0xFFFFFC00u;
      unsigned fb = (bp & 0x80000000u) ? (bp ^ 0x80000000u) : ~bp;
      float thrf = __uint_as_float(fb) + WWIN;
      unsigned tu = __float_as_uint(thrf);
      tu ^= (unsigned)((int)tu >> 31) | 0x80000000u;
      thrU[r] = tu | 1023u;                 // inclusive of code bits
    }
    if (__any(pm <= thrU[r])){              // fast-skip most chunks
      const int tok = tok0 + w*16 + lq*4 + r;
      int base = cntR[r];
      #pragma unroll
      for (int ni = 0; ni < 4; ni++){
        const unsigned p = pv[ni];
        const bool pass = (p <= thrU[r]);
        unsigned long long bal = __ballot(pass);
        const unsigned bq = (unsigned)(bal >> (lq*16)) & 0xFFFFu;
        if (pass){
          int pos = base + __popc(bq & ((1u << li) - 1u));
          if (pos < CCAP)
            candW[(size_t)tok*CCAP + pos] = (unsigned short)(p & 1023u);
        }
        base += __popc(bq);
      }
      cntR[r] = base;
    }
  }
}

// ---------- phase 1: A-in-register MFMA sweep, pipelined epilogue ----------
// 512 threads = 8 waves; wave w owns tokens [bId*128 + w*16, +16).
// Chunk c's MFMAs issue, then chunk c-1's epilogue runs (accA/accB ping-pong).
// Dump: cntW written for ALL tokens; light tokens finalized; heavy get abestW.
__global__ __launch_bounds__(512, 4) void vq_sweep_k(const float* __restrict__ z,
                                                     const uint4* __restrict__ Bg,
                                                     const float* __restrict__ cnG,
                                                     int* __restrict__ cntW,
                                                     unsigned short* __restrict__ candW,
                                                     int* __restrict__ abestW,
                                                     int* __restrict__ idsW,
                                                     float* __restrict__ out){
  __shared__ uint4 Bs[2][2048];    // 64 KiB: [buf][dc 0..7][kq 0..3][n 0..63]
  __shared__ float cnS[1024];      // 4 KiB

  const int tid = threadIdx.x, bId = blockIdx.x;
  const int w = tid >> 6, ln = tid & 63;
  const int li = ln & 15, lq = ln >> 4;

  // ---- stage cn (4 KiB) + B chunk 0 first (overlaps the A-load below) ----
  if (w < 4) dma16((const uint4*)cnG + w*64 + ln, (uint4*)&cnS[w*256]);
  int bOff[4];
  #pragma unroll
  for (int j = 0; j < 4; j++){
    const int f = j*512 + tid;              // [dc][kq][nl] flat
    bOff[j] = (f >> 8)*1024 + ((f >> 6) & 3)*256 + (f & 63);
  }
  #pragma unroll
  for (int j = 0; j < 4; j++)
    dma16(Bg + bOff[j], &Bs[0][j*512 + w*64]);

  // ---- A: z -> bf16 frags in registers (verified bf16pk chain) ----
  const int tok0 = bId * 128;
  const int b = tok0 >> 14;                 // uniform per block
  const int s0 = tok0 & 16383;
  const float* zb = z + (size_t)b * Dd * SPB + s0;
  short8 aF[8];
  const int tl = w*16 + li;                 // token within block (A-frag row)
  #pragma unroll
  for (int kk = 0; kk < 8; kk++){
    float v[8];
    #pragma unroll
    for (int j = 0; j < 8; j++)
      v[j] = zb[(size_t)(kk*32 + lq*8 + j) * SPB + tl];
    union { unsigned u[4]; short8 s8; } x;
    #pragma unroll
    for (int p = 0; p < 4; p++) x.u[p] = bf16pk(v[2*p], v[2*p+1]);
    aF[kk] = x.s8;
  }

  unsigned bestR[4], thrU[4]; int cntR[4];
  #pragma unroll
  for (int i = 0; i < 4; i++){ bestR[i] = 0xFFFFFFFFu; thrU[i] = 0u; cntR[i] = 0; }

  v4f accA[4], accB[4];
  const v4f vz = {0.f, 0.f, 0.f, 0.f};

  for (int cp = 0; cp < 8; cp++){
    const int c0 = cp*2, c1 = c0 + 1;

    // ===== chunk c0 (buf 0) =====
    {
      const int cn1 = c0 + 1;                       // <=15 always
      const int srcB = (cn1 >> 2)*8192 + (cn1 & 3)*64;
      #pragma unroll
      for (int j = 0; j < 4; j++)
        dma16(Bg + srcB + bOff[j], &Bs[1][j*512 + w*64]);
      asm volatile("s_waitcnt vmcnt(4)" ::: "memory");   // chunk c0 loads done
      __builtin_amdgcn_s_barrier();
      asm volatile("" ::: "memory");

      #pragma unroll
      for (int ni = 0; ni < 4; ni++) accA[ni] = vz;
      const uint4* Bbase = &Bs[0][lq*64 + li];
      __builtin_amdgcn_s_setprio(1);
      #pragma unroll
      for (int kk = 0; kk < 8; kk++){               // dc ascending: same K-order
        short8 b0 = frg(Bbase[kk*256 +  0]);
        short8 b1 = frg(Bbase[kk*256 + 16]);
        short8 b2 = frg(Bbase[kk*256 + 32]);
        short8 b3 = frg(Bbase[kk*256 + 48]);
        accA[0] = mfma16(aF[kk], b0, accA[0]);
        accA[1] = mfma16(aF[kk], b1, accA[1]);
        accA[2] = mfma16(aF[kk], b2, accA[2]);
        accA[3] = mfma16(aF[kk], b3, accA[3]);
      }
      __builtin_amdgcn_s_setprio(0);
      if (cp)                                        // epilogue for chunk c0-1
        epi(accB, c0 - 1, li, lq, w, tok0, cnS, bestR, thrU, cntR, candW);
      __builtin_amdgcn_s_barrier();                  // buf0 reads done
      asm volatile("" ::: "memory");
    }

    // ===== chunk c1 (buf 1) =====
    {
      if (c1 < 15){
        const int cn1 = c1 + 1;                      // even -> buf 0
        const int srcB = (cn1 >> 2)*8192 + (cn1 & 3)*64;
        #pragma unroll
        for (int j = 0; j < 4; j++)
          dma16(Bg + srcB + bOff[j], &Bs[0][j*512 + w*64]);
        asm volatile("s_waitcnt vmcnt(4)" ::: "memory"); // chunk c1 loads done
      } else {
        asm volatile("s_waitcnt vmcnt(0)" ::: "memory");
      }
      __builtin_amdgcn_s_barrier();
      asm volatile("" ::: "memory");

      #pragma unroll
      for (int ni = 0; ni < 4; ni++) accB[ni] = vz;
      const uint4* Bbase = &Bs[1][lq*64 + li];
      __builtin_amdgcn_s_setprio(1);
      #pragma unroll
      for (int kk = 0; kk < 8; kk++){
        short8 b0 = frg(Bbase[kk*256 +  0]);
        short8 b1 = frg(Bbase[kk*256 + 16]);
        short8 b2 = frg(Bbase[kk*256 + 32]);
        short8 b3 = frg(Bbase[kk*256 + 48]);
        accB[0] = mfma16(aF[kk], b0, accB[0]);
        accB[1] = mfma16(aF[kk], b1, accB[1]);
        accB[2] = mfma16(aF[kk], b2, accB[2]);
        accB[3] = mfma16(aF[kk], b3, accB[3]);
      }
      __builtin_amdgcn_s_setprio(0);
      epi(accA, c0, li, lq, w, tok0, cnS, bestR, thrU, cntR, candW);
      __builtin_amdgcn_s_barrier();                  // buf1 reads done
      asm volatile("" ::: "memory");
    }
  }
  epi(accB, 15, li, lq, w, tok0, cnS, bestR, thrU, cntR, candW);

  // ---- final dump: cntW always; light finalized; heavy -> abestW ----
  if (li == 0){
    #pragma unroll
    for (int r = 0; r < 4; r++){
      const int tok = tok0 + w*16 + lq*4 + r;
      cntW[tok] = cntR[r];
      if (cntR[r] == 1){
        const int code = (int)(bestR[r] & 1023u);
        idsW[tok] = code;
        out[(size_t)2 * Nn * Dd + tok] = (float)code;
      } else {
        abestW[tok] = (int)(bestR[r] & 1023u);
      }
    }
  }
}

// ---------- phase 2: fused exact rescore + gather (identity heavy map) ------
// 1 block / 128-token region. Thread tid<128 owns token tid; active iff
// cnt>1. zS reads are bank-conflict-free (lane==tl). Gather: float4-across-
// tokens stores (4 stride-129 LDS reads + 1 dwordx4; 256B segments).
__global__ __launch_bounds__(256) void vq_finish_k(const float* __restrict__ z,
                                                   const float* __restrict__ cb,
                                                   const float* __restrict__ cnG,
                                                   const int* __restrict__ cntW,
                                                   const unsigned short* __restrict__ candW,
                                                   const int* __restrict__ abestW,
                                                   const int* __restrict__ idsW,
                                                   float* __restrict__ out){
  __shared__ __align__(16) float smem[64*129];   // 33 KB: zS[64][128] / tile[64][129]
  __shared__ int idS[128];
  __shared__ int anyH;

  const int tid = threadIdx.x, reg = blockIdx.x;   // 1024 regions
  const int tok0 = reg * 128;
  const int b = tok0 >> 14, sb = tok0 & 16383;

  if (tid == 0) anyH = 0;
  int cntL = 0;
  if (tid < 128){
    idS[tid] = idsW[tok0 + tid];                   // heavy slots overwritten below
    cntL = cntW[tok0 + tid];
  }
  __syncthreads();
  const bool act = (cntL > 1);
  if (act) anyH = 1;
  __syncthreads();

  if (anyH){
    float* zS = smem;                              // [64][128]
    const float* zb = z + (size_t)b * Dd * SPB + sb;

    const int tok = tok0 + tid;                    // == own token (tl = tid)
    const int tl = tid;
    int n = 0, abest = 0;
    bool ovf = false;
    unsigned short cds[CCAP];
    if (act){
      n = cntL;
      ovf = (n > CCAP);
      if (ovf) n = CCAP;
      *(uint4*)&cds[0] = *(const uint4*)&candW[(size_t)tok * CCAP];
      *(uint4*)&cds[8] = *(const uint4*)&candW[(size_t)tok * CCAP + 8];
      abest = abestW[tok];
    }
    const int eIdx = act ? (ovf ? abest : (int)cds[0]) : 0;   // extra (ovf) slot

    float accs[CCAP];
    #pragma unroll
    for (int i = 0; i < CCAP; i++) accs[i] = 0.f;
    float accE = 0.f, za = 0.f;

    for (int ch = 0; ch < 4; ch++){
      if (ch) __syncthreads();                  // protect prior chunk reads
      #pragma unroll
      for (int rr = 0; rr < 8; rr++){
        const int f4 = rr*256 + tid;
        const int row = f4 >> 5, c4 = f4 & 31;
        const float4 v = *(const float4*)(zb + (size_t)(ch*64 + row) * SPB + c4*4);
        *(float4*)&zS[row*128 + c4*4] = v;
      }
      __syncthreads();
      if (act){
        #pragma unroll 8
        for (int d = 0; d < 64; d++){
          const float v = zS[d*128 + tl];
          za = fmaf(v, v, za);
        }
        #pragma unroll
        for (int ci = 0; ci < CCAP; ci++){
          if (ci < n){
            const float* cr = cb + (size_t)cds[ci] * Dd + ch*64;
            float a = accs[ci];
            #pragma unroll
            for (int d = 0; d < 64; d += 4){
              const float4 cv = *(const float4*)(cr + d);
              a = fmaf(zS[(d+0)*128 + tl], cv.x, a);
              a = fmaf(zS[(d+1)*128 + tl], cv.y, a);
              a = fmaf(zS[(d+2)*128 + tl], cv.z, a);
              a = fmaf(zS[(d+3)*128 + tl], cv.w, a);
            }
            accs[ci] = a;
          }
        }
        if (ovf){
          const float* cr = cb + (size_t)eIdx * Dd + ch*64;
          float a = accE;
          #pragma unroll
          for (int d = 0; d < 64; d += 4){
            const float4 cv = *(const float4*)(cr + d);
            a = fmaf(zS[(d+0)*128 + tl], cv.x, a);
            a = fmaf(zS[(d+1)*128 + tl], cv.y, a);
            a = fmaf(zS[(d+2)*128 + tl], cv.z, a);
            a = fmaf(zS[(d+3)*128 + tl], cv.w, a);
          }
          accE = a;
        }
      }
    }

    if (act){
      float bv = 3.4e38f; int bi = 0x7fffffff;
      #pragma unroll
      for (int ci = 0; ci < CCAP; ci++){
        if (ci < n){
          const int ix = (int)cds[ci];
          float t  = za - 2.0f * accs[ci];
          float d2 = t + cnG[ix];
          if (d2 < bv || (d2 == bv && ix < bi)){ bv = d2; bi = ix; }
        }
      }
      if (ovf){
        float t  = za - 2.0f * accE;
        float d2 = t + cnG[eIdx];
        if (d2 < bv || (d2 == bv && eIdx < bi)){ bv = d2; bi = eIdx; }
      }
      idS[tl] = bi;
      out[(size_t)2 * Nn * Dd + tok] = (float)bi;
    }
  }
  __syncthreads();                                 // idS final, smem free

  // ---- gather: load (proven scalar map) + float4-across-tokens stores ----
  float* tile = smem;                              // [64][129]
  const int r2 = tid >> 7, ccol = tid & 127;       // load mapping
  const int s4 = tid & 15, d16 = tid >> 4;         // store mapping
  for (int hh = 0; hh < 2; hh++){
    const int s0h = hh * 64;
    float* qb  = out + (size_t)b * Dd * SPB + sb + s0h + s4*4;
    float* stb = qb + (size_t)Nn * Dd;
    for (int ch = 0; ch < 2; ch++){
      if (hh | ch) __syncthreads();                // protect prior tile reads
      #pragma unroll 4
      for (int t0 = 0; t0 < 64; t0 += 2){
        const int row = t0 + r2;
        tile[row*129 + ccol] = cb[(size_t)idS[s0h + row] * Dd + ch*128 + ccol];
      }
      __syncthreads();
      #pragma unroll
      for (int k = 0; k < 8; k++){
        const int dcol = d16 + 16*k;
        float4 v;
        v.x = tile[(s4*4 + 0)*129 + dcol];
        v.y = tile[(s4*4 + 1)*129 + dcol];
        v.z = tile[(s4*4 + 2)*129 + dcol];
        v.w = tile[(s4*4 + 3)*129 + dcol];
        const size_t off = (size_t)(ch*128 + dcol) * SPB;
        *(float4*)(qb  + off) = v;
        *(float4*)(stb + off) = v;
      }
    }
  }
}

// ================= R1 fp32 fallback (used if ws too small) =================
#define MICRO_STEP(WITH_ZN)                                                    \
    {                                                                          \
        float4 a0 = *(const float4*)&As[d][ty * 8];                            \
        float4 a1 = *(const float4*)&As[d][ty * 8 + 4];                        \
        float4 b0 = *(const float4*)&Bs[d][tx * 8];                            \
        float4 b1 = *(const float4*)&Bs[d][tx * 8 + 4];                        \
        float a[8] = {a0.x, a0.y, a0.z, a0.w, a1.x, a1.y, a1.z, a1.w};         \
        float bb[8] = {b0.x, b0.y, b0.z, b0.w, b1.x, b1.y, b1.z, b1.w};        \
        _Pragma("unroll")                                                      \
        for (int i = 0; i < 8; i++) {                                          \
            _Pragma("unroll")                                                  \
            for (int j = 0; j < 8; j++) acc[i][j] += a[i] * bb[j];             \
            if (WITH_ZN) zn[i] += a[i] * a[i];                                 \
        }                                                                      \
    }

__global__ __launch_bounds__(256) void vq_k(const float* __restrict__ z,
                                            const float* __restrict__ cb,
                                            const float* __restrict__ cn,
                                            float* __restrict__ out){
  __shared__ float As[16][128];
  __shared__ float Bs[16][132];
  __shared__ int   idsf[128];
  const int tid = threadIdx.x;
  const int tx = tid & 15, ty = tid >> 4;
  const int blk = blockIdx.x;
  const int b = blk >> 7, sb = (blk & 127) * 128;
  const float* zb = z + (size_t)b * Dd * SPB + sb;
  float bestv[8]; int besti[8]; float zn[8];
  #pragma unroll
  for (int i = 0; i < 8; i++){ bestv[i] = 3.4e38f; besti[i] = 0; zn[i] = 0.f; }
  const int am = tid & 127, ad = tid >> 7;
  const int bd = tid & 15,  bk = tid >> 4;
  for (int cc = 0; cc < 8; cc++){
    float acc[8][8];
    #pragma unroll
    for (int i = 0; i < 8; i++)
      #pragma unroll
      for (int j = 0; j < 8; j++) acc[i][j] = 0.f;
    for (int dc = 0; dc < 16; dc++){
      #pragma unroll
      for (int r = 0; r < 8; r++){
        const int d = ad + r * 2;
        As[d][am] = zb[(size_t)(dc*16 + d) * SPB + am];
      }
      #pragma unroll
      for (int r = 0; r < 8; r++){
        const int k = bk + r * 16;
        Bs[bd][k] = cb[(size_t)(cc*128 + k) * Dd + dc*16 + bd];
      }
      __syncthreads();
      if (cc == 0){
        #pragma unroll
        for (int d = 0; d < 16; d++) MICRO_STEP(1)
      } else {
        #pragma unroll
        for (int d = 0; d < 16; d++) MICRO_STEP(0)
      }
      __syncthreads();
    }
    const float* cnp = cn + cc*128 + tx*8;
    float4 c0 = *(const float4*)cnp;
    float4 c1 = *(const float4*)(cnp + 4);
    float cv[8] = {c0.x, c0.y, c0.z, c0.w, c1.x, c1.y, c1.z, c1.w};
    #pragma unroll
    for (int i = 0; i < 8; i++){
      #pragma unroll
      for (int j = 0; j < 8; j++){
        float t  = zn[i] - 2.0f * acc[i][j];
        float d2 = t + cv[j];
        int   ix = cc*128 + tx*8 + j;
        if (d2 < bestv[i]){ bestv[i] = d2; besti[i] = ix; }
      }
    }
  }
  #pragma unroll
  for (int i = 0; i < 8; i++){
    float v = bestv[i]; int ix = besti[i];
    #pragma unroll
    for (int off = 8; off > 0; off >>= 1){
      float ov = __shfl_down(v, off, 16);
      int   oi = __shfl_down(ix, off, 16);
      if (ov < v || (ov == v && oi < ix)){ v = ov; ix = oi; }
    }
    if (tx == 0) idsf[ty*8 + i] = ix;
  }
  __syncthreads();
  if (tid < 128) out[(size_t)2*Nn*Dd + (size_t)blk*128 + tid] = (float)idsf[tid];
  const int m = tid & 127, cg = tid >> 7;
  const int myidx = idsf[m];
  const float* crow = cb + (size_t)myidx * Dd + cg*128;
  float* q  = out + (size_t)b * Dd * SPB + (size_t)cg * 128 * SPB + sb + m;
  float* st = q + (size_t)Nn * Dd;
  #pragma unroll 8
  for (int r = 0; r < 128; r++){
    const float v = crow[r];
    q[(size_t)r * SPB]  = v;
    st[(size_t)r * SPB] = v;
  }
}

// ---------- launcher ----------
extern "C" void kernel_launch(void* const* d_in, const int* in_sizes, int n_in,
                              void* d_out, int out_size, void* d_ws, size_t ws_size,
                              hipStream_t stream){
  const float* z  = (const float*)d_in[0];
  const float* cb = (const float*)d_in[1];
  float* out = (float*)d_out;

  const size_t BG_B  = (size_t)4 * 8 * 1024 * 16;     // 512 KiB
  const size_t CN_B  = (size_t)Kk * 4;                // 4 KiB
  const size_t CNT_B = (size_t)Nn * 4;                // 512 KiB
  const size_t CAN_B = (size_t)Nn * CCAP * 2;         // 4 MiB
  const size_t ABW_B = (size_t)Nn * 4;                // 512 KiB
  const size_t IDS_B = (size_t)Nn * 4;                // 512 KiB
  const size_t NEED = BG_B + CN_B + CNT_B + CAN_B + ABW_B + IDS_B;

  if (ws_size >= NEED){
    uint8_t* ws = (uint8_t*)d_ws;
    size_t o = 0;
    uint4* Bg   = (uint4*)(ws + o);          o += BG_B;
    float* cnG  = (float*)(ws + o);          o += CN_B;
    int*   cntW = (int*)(ws + o);            o += CNT_B;
    unsigned short* candW = (unsigned short*)(ws + o); o += CAN_B;
    int*   abW  = (int*)(ws + o);            o += ABW_B;
    int*   idsW = (int*)(ws + o);            o += IDS_B;

    cnorm_k<<<Kk, 64, 0, stream>>>(cb, cnG);
    cconv_k<<<4, 256, 0, stream>>>(cb, Bg);
    vq_sweep_k<<<Nn/128, 512, 0, stream>>>(z, Bg, cnG, cntW, candW, abW,
                                           idsW, out);
    vq_finish_k<<<Nn/128, 256, 0, stream>>>(z, cb, cnG, cntW, candW, abW,
                                            idsW, out);
  } else {
    float* cn = (float*)d_ws;
    cnorm_k<<<Kk, 64, 0, stream>>>(cb, cn);
    vq_k<<<Nn/128, 256, 0, stream>>>(z, cb, cn, out);
  }
}